// Round 9
// baseline (707.793 us; speedup 1.0000x reference)
//
#include <hip/hip_runtime.h>
#include <math.h>

#define N_NODES 40000
#define M_PAD   40064      // 313 * 128
#define N_EDGES 640000
#define D       256
#define H       8
#define DFF     1024
#define D3      768
#define ATT_SCALE 0.0625f  // 256^-0.5
#define LN_EPS  1e-5f

typedef __attribute__((ext_vector_type(8))) short short8;
typedef __attribute__((ext_vector_type(4))) float f32x4;
typedef __attribute__((ext_vector_type(2))) float f32x2;

__device__ __forceinline__ unsigned short f2bf(float f) {
    unsigned int u = __builtin_bit_cast(unsigned int, f);
    u = (u + 0x7FFF + ((u >> 16) & 1)) >> 16;   // RTNE
    return (unsigned short)u;
}
__device__ __forceinline__ float bf2f(unsigned short u) {
    return __builtin_bit_cast(float, (unsigned int)u << 16);
}

// Fast exact-gelu: Abramowitz-Stegun 7.1.26 erf (|eps| <= 1.5e-7, branchless).
__device__ __forceinline__ float fast_gelu(float x) {
    const float z  = fabsf(x) * 0.70710678118654752f;
    const float t  = __builtin_amdgcn_rcpf(1.0f + 0.3275911f * z);
    float p = 1.061405429f;
    p = p * t - 1.453152027f;
    p = p * t + 1.421413741f;
    p = p * t - 0.284496736f;
    p = p * t + 0.254829592f;
    const float e  = __expf(-z * z);
    const float ea = 1.0f - p * t * e;          // erf(|x|/sqrt2)
    const float er = (x < 0.0f) ? -ea : ea;
    return 0.5f * x * (1.0f + er);
}

#define GLOAD_LDS16(g, l) \
    __builtin_amdgcn_global_load_lds((const __attribute__((address_space(1))) void*)(g), \
                                     (__attribute__((address_space(3))) void*)(l), 16, 0, 0)

// ---------------- fp8 e4m3 pack/unpack (HW cvt on gfx950, SW fallback) -----
#if __has_builtin(__builtin_amdgcn_cvt_pk_fp8_f32) && __has_builtin(__builtin_amdgcn_cvt_pk_f32_fp8)
#define HW_FP8 1
#else
#define HW_FP8 0
__device__ __forceinline__ unsigned char enc_e4m3(float f) {
    unsigned int u = __builtin_bit_cast(unsigned int, f);
    unsigned int s = (u >> 24) & 0x80;
    float a = fabsf(f);
    if (a >= 0x1p-6f) {
        unsigned int bits = __builtin_bit_cast(unsigned int, a);
        unsigned int q = bits >> 20;
        unsigned int rem = bits & 0xFFFFFu;
        q += (rem > 0x80000u) || ((rem == 0x80000u) && (q & 1));
        q -= 960;                          // rebias (120<<3)
        if (q > 126) q = 126;              // clamp to 448
        return (unsigned char)(s | q);
    }
    float t = a * 512.0f;
    unsigned int r = (unsigned int)rintf(t);   // RNE; 8 -> min normal naturally
    return (unsigned char)(s | r);
}
__device__ __forceinline__ float dec_e4m3(unsigned int v) {
    unsigned int em = v & 0x7f;
    float n = __builtin_bit_cast(float, (em << 20) + 0x3C000000u);
    float r = (em >= 8) ? n : (float)em * 0x1p-9f;
    return (v & 0x80) ? -r : r;
}
#endif

__device__ __forceinline__ unsigned int pack4_e4m3(float a, float b, float c, float d) {
#if HW_FP8
    unsigned int w = (unsigned int)__builtin_amdgcn_cvt_pk_fp8_f32(a, b, 0, false);
    w = (unsigned int)__builtin_amdgcn_cvt_pk_fp8_f32(c, d, (int)w, true);
    return w;
#else
    return (unsigned int)enc_e4m3(a) | ((unsigned int)enc_e4m3(b) << 8)
         | ((unsigned int)enc_e4m3(c) << 16) | ((unsigned int)enc_e4m3(d) << 24);
#endif
}
__device__ __forceinline__ void dec4_e4m3(unsigned int w, float& a, float& b, float& c, float& d) {
#if HW_FP8
    f32x2 lo = __builtin_amdgcn_cvt_pk_f32_fp8((int)w, false);
    f32x2 hi = __builtin_amdgcn_cvt_pk_f32_fp8((int)w, true);
    a = lo[0]; b = lo[1]; c = hi[0]; d = hi[1];
#else
    a = dec_e4m3(w & 0xff); b = dec_e4m3((w >> 8) & 0xff);
    c = dec_e4m3((w >> 16) & 0xff); d = dec_e4m3(w >> 24);
#endif
}

// ---------------------------------------------------------------------------
// LayerNorm -> bf16 output in MFMA A-fragment order [M/16][D/8][16][8].
// Covers pad rows [N_NODES, M_PAD) with zeros (replaces a memset).
// ---------------------------------------------------------------------------
__global__ __launch_bounds__(256) void ln_bf_kernel(const float* __restrict__ in,
                                                    const float* __restrict__ g,
                                                    const float* __restrict__ b,
                                                    unsigned short* __restrict__ out)
{
    const int row  = blockIdx.x * 4 + (threadIdx.x >> 6);
    const int lane = threadIdx.x & 63;
    const size_t off = (((size_t)(row >> 4) * (D / 8) + (lane >> 1)) * 16 + (row & 15)) * 8
                       + (lane & 1) * 4;
    if (row >= N_NODES) {
        ushort4 z = {0, 0, 0, 0};
        *reinterpret_cast<ushort4*>(out + off) = z;
        return;
    }
    const float4 v = *reinterpret_cast<const float4*>(in + (size_t)row * D + lane * 4);
    float s  = v.x + v.y + v.z + v.w;
    float s2 = v.x * v.x + v.y * v.y + v.z * v.z + v.w * v.w;
#pragma unroll
    for (int o = 32; o > 0; o >>= 1) {
        s  += __shfl_xor(s,  o, 64);
        s2 += __shfl_xor(s2, o, 64);
    }
    const float mu  = s * (1.0f / D);
    const float var = s2 * (1.0f / D) - mu * mu;
    const float rs  = rsqrtf(var + LN_EPS);
    const float4 gg = *reinterpret_cast<const float4*>(g + lane * 4);
    const float4 bb = *reinterpret_cast<const float4*>(b + lane * 4);
    ushort4 o4;
    o4.x = f2bf((v.x - mu) * rs * gg.x + bb.x);
    o4.y = f2bf((v.y - mu) * rs * gg.y + bb.y);
    o4.z = f2bf((v.z - mu) * rs * gg.z + bb.z);
    o4.w = f2bf((v.w - mu) * rs * gg.w + bb.w);
    *reinterpret_cast<ushort4*>(out + off) = o4;
}

// ---------------------------------------------------------------------------
// Weight pack: W[K][N] fp32 -> bf16 packed [N/16][K/8][16][8]. All three
// weights in ONE kernel (one launch).
// ---------------------------------------------------------------------------
template <int K, int N>
__device__ __forceinline__ void pack_body(const float* __restrict__ W,
                                          unsigned short* __restrict__ Wpk, int blk)
{
    const int idx = blk * 256 + threadIdx.x;   // [N/16][K/8][16]
    const int ni  = idx & 15;
    const int kc  = (idx >> 4) % (K / 8);
    const int nt  = idx / (16 * (K / 8));
    const int n   = nt * 16 + ni;
    unsigned short o[8];
#pragma unroll
    for (int i = 0; i < 8; ++i)
        o[i] = f2bf(W[(size_t)(kc * 8 + i) * N + n]);
    *reinterpret_cast<short8*>(Wpk + (size_t)idx * 8) = *reinterpret_cast<short8*>(o);
}

__global__ __launch_bounds__(256) void pack_all_kernel(const float* __restrict__ Wqkv,
                                                       const float* __restrict__ W_in,
                                                       const float* __restrict__ W_out,
                                                       unsigned short* __restrict__ pq,
                                                       unsigned short* __restrict__ pi,
                                                       unsigned short* __restrict__ po)
{
    const int b = blockIdx.x;
    if (b < 96)       pack_body<D, D3 >(Wqkv, pq, b);
    else if (b < 224) pack_body<D, DFF>(W_in, pi, b - 96);
    else              pack_body<DFF, D>(W_out, po, b - 224);
}

// ---------------------------------------------------------------------------
// bf16 MFMA GEMM (qkv only now) -- m97 staging structure, 128x128 tile,
// 4 waves, BK=32, global_load_lds width 16, LDS 16 KB, 4 blocks/CU.
// Panel-colocating XCD swizzle. MFMA operands SWAPPED: D maps to row
// r = lane&15, cols n = (lane>>4)*4+t -> 4 consecutive cols per thread.
// EPI 0: qkv 3-way split -> q fp8 (unscaled), k bf16 [node][256], v fp8
// ---------------------------------------------------------------------------
template <int EPI, int K, int N>
__global__ __launch_bounds__(256, 4) void mfma_gemm_kernel(const unsigned short* __restrict__ A,
                                                           const unsigned short* __restrict__ Bpk,
                                                           const float* __restrict__ bias,
                                                           void* __restrict__ Cout,
                                                           void* __restrict__ Cout2,
                                                           void* __restrict__ Cout3)
{
    constexpr int C = N / 128;           // col tiles
    constexpr int P = M_PAD / 128;       // 313 row panels

    const int bid = blockIdx.x;
    const int xcd = bid & 7;
    const int t   = bid >> 3;
    const int c   = t % C;
    const int p   = (t / C) * 8 + xcd;
    if (p >= P) return;

    __shared__ unsigned short As[4096];   // [mt8][16][8] = 8 KB
    __shared__ unsigned short Bs[4096];

    const int tid  = threadIdx.x;
    const int wave = tid >> 6;
    const int lane = tid & 63;
    const int row0 = p * 128;
    const int col0 = c * 128;
    const int wm   = (wave >> 1) * 64;
    const int wn   = (wave & 1) * 64;
    const int g    = lane >> 4;
    const int q    = lane & 15;

    f32x4 acc[4][4] = {};

    const int fragoff = g * 128 + q * 8;

    for (int k0 = 0; k0 < K; k0 += 32) {
        const int kq = k0 >> 3;   // k-chunk index (K/8 units)
#pragma unroll
        for (int cc = 0; cc < 2; ++cc) {
            const int mt = wave * 2 + cc;                // 0..7
            const unsigned short* gA =
                A + ((size_t)(row0 / 16 + mt) * (K / 8) + kq) * 128 + lane * 8;
            GLOAD_LDS16(gA, &As[mt * 512]);
            const unsigned short* gB =
                Bpk + ((size_t)(col0 / 16 + mt) * (K / 8) + kq) * 128 + lane * 8;
            GLOAD_LDS16(gB, &Bs[mt * 512]);
        }
        __syncthreads();

        short8 af[4], bf[4];
#pragma unroll
        for (int i = 0; i < 4; ++i) {
            af[i] = *reinterpret_cast<const short8*>(&As[(wm / 16 + i) * 512 + fragoff]);
            bf[i] = *reinterpret_cast<const short8*>(&Bs[(wn / 16 + i) * 512 + fragoff]);
        }
#pragma unroll
        for (int i = 0; i < 4; ++i)
#pragma unroll
            for (int j = 0; j < 4; ++j)
                acc[i][j] = __builtin_amdgcn_mfma_f32_16x16x32_bf16(bf[j], af[i], acc[i][j], 0, 0, 0);
        __syncthreads();
    }

    // Swapped D layout: r = row0+wm+i*16+q ; n = col0+wn+j*16+g*4+t (t=0..3)
    if (col0 < 256) {        // q cols -> fp8, UNSCALED (scale folded into k)
        unsigned char* q8 = (unsigned char*)Cout;
#pragma unroll
        for (int j = 0; j < 4; ++j) {
            const int nb = col0 + wn + j * 16 + g * 4;
            const float4 bz = *reinterpret_cast<const float4*>(bias + nb);
#pragma unroll
            for (int i = 0; i < 4; ++i) {
                const int r = row0 + wm + i * 16 + q;
                if (r >= N_NODES) continue;
                const unsigned int w = pack4_e4m3(acc[i][j][0] + bz.x, acc[i][j][1] + bz.y,
                                                  acc[i][j][2] + bz.z, acc[i][j][3] + bz.w);
                *reinterpret_cast<unsigned int*>(q8 + (size_t)r * 256 + nb) = w;
            }
        }
    } else if (col0 < 512) { // k cols -> bf16 row-major [node][256]
        unsigned short* kb = (unsigned short*)Cout2;
#pragma unroll
        for (int j = 0; j < 4; ++j) {
            const int nb = col0 + wn + j * 16 + g * 4;
            const float4 bz = *reinterpret_cast<const float4*>(bias + nb);
#pragma unroll
            for (int i = 0; i < 4; ++i) {
                const int r = row0 + wm + i * 16 + q;
                if (r >= N_NODES) continue;
                ushort4 u;
                u.x = f2bf(acc[i][j][0] + bz.x);
                u.y = f2bf(acc[i][j][1] + bz.y);
                u.z = f2bf(acc[i][j][2] + bz.z);
                u.w = f2bf(acc[i][j][3] + bz.w);
                *reinterpret_cast<ushort4*>(kb + (size_t)r * 256 + (nb - 256)) = u;
            }
        }
    } else {                 // v cols -> fp8 [node][256]
        unsigned char* v8 = (unsigned char*)Cout3;
#pragma unroll
        for (int j = 0; j < 4; ++j) {
            const int nb = col0 + wn + j * 16 + g * 4;
            const float4 bz = *reinterpret_cast<const float4*>(bias + nb);
#pragma unroll
            for (int i = 0; i < 4; ++i) {
                const int r = row0 + wm + i * 16 + q;
                if (r >= N_NODES) continue;
                const unsigned int w = pack4_e4m3(acc[i][j][0] + bz.x, acc[i][j][1] + bz.y,
                                                  acc[i][j][2] + bz.z, acc[i][j][3] + bz.w);
                *reinterpret_cast<unsigned int*>(v8 + (size_t)r * 256 + (nb - 512)) = w;
            }
        }
    }
}

// ---------------------------------------------------------------------------
// Fused FFN: out = x + gelu(xn @ W_in + b_in) @ W_out + b_out.
// One block per 64-row panel (626 blocks). Loops DFF in 8 chunks of 128:
// GEMM1 chunk (K=256) -> gelu -> pack to 16 KB LDS tile (GEMM2-A fragment
// order) -> barrier -> GEMM2 accumulate (K=128 of 1024) into persistent
// 64x256 fp32 acc. Eliminates the 164 MB a1 HBM round-trip + one dispatch.
// Wave split: rows (wave&1)*32, GEMM1 cols (wave>>1)*64, GEMM2 cols
// (wave>>1)*128. Swapped MFMA throughout (r = lane&15).
// ---------------------------------------------------------------------------
__global__ __launch_bounds__(256, 3) void fused_ffn_kernel(const unsigned short* __restrict__ A,
                                                           const unsigned short* __restrict__ Wi,
                                                           const unsigned short* __restrict__ Wo,
                                                           const float* __restrict__ b_in,
                                                           const float* __restrict__ b_out,
                                                           const float* __restrict__ x,
                                                           float* __restrict__ out)
{
    __shared__ unsigned short a1c[8192];   // [mt4][kc16][16][8] = 16 KB

    const int p    = blockIdx.x;           // 64-row panel, 0..625
    const int tid  = threadIdx.x;
    const int wave = tid >> 6;
    const int lane = tid & 63;
    const int g    = lane >> 4;
    const int q    = lane & 15;
    const int wrow = (wave & 1) * 2;       // row mt offset (rows wrow*16..+31)
    const int wc1  = (wave >> 1) * 4;      // GEMM1 chunk-col nt offset (cols wc1*16..+63)
    const int wc2  = (wave >> 1) * 8;      // GEMM2 out-col nt offset (cols wc2*16..+127)

    f32x4 acc2[2][8] = {};

#pragma unroll 1
    for (int ch = 0; ch < 8; ++ch) {
        // ---- GEMM1 chunk: a1[64][128] = xn[64][256] @ W_in[:, ch*128..+127]
        f32x4 acc1[2][4] = {};
#pragma unroll
        for (int ks = 0; ks < 8; ++ks) {
            const int kc = ks * 4 + g;     // K/8 index, 0..31
            short8 ah[2], bw[4];
#pragma unroll
            for (int i = 0; i < 2; ++i)
                ah[i] = *reinterpret_cast<const short8*>(
                    A + ((size_t)(p * 4 + wrow + i) * 32 + kc) * 128 + q * 8);
#pragma unroll
            for (int j = 0; j < 4; ++j) {
                const int nt = ch * 8 + wc1 + j;   // DFF/16 index
                bw[j] = *reinterpret_cast<const short8*>(
                    Wi + ((size_t)nt * 32 + kc) * 128 + q * 8);
            }
#pragma unroll
            for (int i = 0; i < 2; ++i)
#pragma unroll
                for (int j = 0; j < 4; ++j)
                    acc1[i][j] = __builtin_amdgcn_mfma_f32_16x16x32_bf16(bw[j], ah[i], acc1[i][j], 0, 0, 0);
        }
        __syncthreads();   // prev chunk's GEMM2 reads complete

        // ---- gelu + pack to LDS in GEMM2-A fragment order
#pragma unroll
        for (int j = 0; j < 4; ++j) {
            const int cb = (wc1 + j) * 16 + g * 4;       // chunk-local col 0..127
            const float4 bz = *reinterpret_cast<const float4*>(b_in + ch * 128 + cb);
            const int kc = cb >> 3;
            const int ki = (g & 1) * 4;
#pragma unroll
            for (int i = 0; i < 2; ++i) {
                ushort4 u;
                u.x = f2bf(fast_gelu(acc1[i][j][0] + bz.x));
                u.y = f2bf(fast_gelu(acc1[i][j][1] + bz.y));
                u.z = f2bf(fast_gelu(acc1[i][j][2] + bz.z));
                u.w = f2bf(fast_gelu(acc1[i][j][3] + bz.w));
                *reinterpret_cast<ushort4*>(
                    &a1c[(((wrow + i) * 16 + kc) * 16 + q) * 8 + ki]) = u;
            }
        }
        __syncthreads();   // a1c visible

        // ---- GEMM2 accumulate: acc2 += a1[64][128] @ W_out[ch*128..+127][256]
#pragma unroll
        for (int ks = 0; ks < 4; ++ks) {
            const int kc = ks * 4 + g;     // chunk-local K/8, 0..15
            short8 aa[2], bw[8];
#pragma unroll
            for (int i = 0; i < 2; ++i)
                aa[i] = *reinterpret_cast<const short8*>(
                    &a1c[(((wrow + i) * 16 + kc) * 16 + q) * 8]);
#pragma unroll
            for (int j = 0; j < 8; ++j) {
                const int nt = wc2 + j;                 // 0..15 (N=256)
                const int kcg = ch * 16 + kc;           // global K/8 of DFF
                bw[j] = *reinterpret_cast<const short8*>(
                    Wo + ((size_t)nt * 128 + kcg) * 128 + q * 8);
            }
#pragma unroll
            for (int i = 0; i < 2; ++i)
#pragma unroll
                for (int j = 0; j < 8; ++j)
                    acc2[i][j] = __builtin_amdgcn_mfma_f32_16x16x32_bf16(bw[j], aa[i], acc2[i][j], 0, 0, 0);
        }
    }

    // ---- epilogue: out = acc2 + b_out + x (rows r = p*64 + (wrow+i)*16 + q)
#pragma unroll
    for (int j = 0; j < 8; ++j) {
        const int col = (wc2 + j) * 16 + g * 4;
        const float4 bz = *reinterpret_cast<const float4*>(b_out + col);
#pragma unroll
        for (int i = 0; i < 2; ++i) {
            const int r = p * 64 + (wrow + i) * 16 + q;
            if (r >= N_NODES) continue;
            const f32x4 xd = __builtin_nontemporal_load(
                reinterpret_cast<const f32x4*>(x + (size_t)r * D + col));
            f32x4 ov;
            ov[0] = acc2[i][j][0] + bz.x + xd[0];
            ov[1] = acc2[i][j][1] + bz.y + xd[1];
            ov[2] = acc2[i][j][2] + bz.z + xd[2];
            ov[3] = acc2[i][j][3] + bz.w + xd[3];
            __builtin_nontemporal_store(ov,
                reinterpret_cast<f32x4*>(out + (size_t)r * D + col));
        }
    }
}

// ---------------------------------------------------------------------------
// CSR build
// ---------------------------------------------------------------------------
__global__ __launch_bounds__(256) void hist_kernel(const int* __restrict__ dst,
                                                   int* __restrict__ counts)
{
    const int i = blockIdx.x * 256 + threadIdx.x;
    atomicAdd(&counts[dst[i]], 1);
}

// Two-pass, ARRAY-FREE scan (int c[40] spilled to scratch -> was 64 us).
__global__ __launch_bounds__(1024) void scan_kernel(const int* __restrict__ counts,
                                                    int* __restrict__ rowptr,
                                                    int* __restrict__ cursor)
{
    const int PER = 40;
    const int tid  = threadIdx.x;
    const int base = tid * PER;
    const bool act = (base < N_NODES);     // threads 0..999 own 40 each
    int s = 0;
    if (act) {
#pragma unroll
        for (int i = 0; i < PER / 4; ++i) {
            const int4 c4 = *reinterpret_cast<const int4*>(counts + base + i * 4);
            s += (c4.x + c4.y) + (c4.z + c4.w);
        }
    }
    __shared__ int sm[1024];
    sm[tid] = s;
    __syncthreads();
    for (int off = 1; off < 1024; off <<= 1) {
        int t = (tid >= off) ? sm[tid - off] : 0;
        __syncthreads();
        sm[tid] += t;
        __syncthreads();
    }
    int run = sm[tid] - s;                 // exclusive prefix of this chunk
    if (act) {
#pragma unroll
        for (int i = 0; i < PER / 4; ++i) {
            const int4 c4 = *reinterpret_cast<const int4*>(counts + base + i * 4);
            int4 r4;
            r4.x = run;
            r4.y = r4.x + c4.x;
            r4.z = r4.y + c4.y;
            r4.w = r4.z + c4.z;
            run  = r4.w + c4.w;
            *reinterpret_cast<int4*>(rowptr + base + i * 4) = r4;
            *reinterpret_cast<int4*>(cursor + base + i * 4) = r4;
        }
    }
    if (tid == 1023) rowptr[N_NODES] = sm[1023];
}

__global__ __launch_bounds__(256) void fill_kernel(const int* __restrict__ src,
                                                   const int* __restrict__ dst,
                                                   int* __restrict__ cursor,
                                                   int* __restrict__ srcs)
{
    const int e = blockIdx.x * 256 + threadIdx.x;
    const int pos = atomicAdd(&cursor[dst[e]], 1);
    if (pos >= 0 && pos < N_EDGES) srcs[pos] = src[e];
}

// ---------------------------------------------------------------------------
// Fused attention: q fp8 (256 B/row, gathered) + v fp8 (256 B/row, gathered)
// + k bf16 (512 B/row, loaded once per dst node). Edge gather = 512 B.
// One wave per dst node; src list coalesce-prefetched, readlane broadcast,
// 4-edge unroll. k scaled by ATT_SCALE at load.
// Outputs: x fp32 row-major, xn bf16 in fragment order.
// ---------------------------------------------------------------------------
__global__ __launch_bounds__(256) void fused_attn_kernel(const unsigned char* __restrict__ qf8,
                                                         const unsigned short* __restrict__ kbf,
                                                         const unsigned char* __restrict__ vf8,
                                                         const int* __restrict__ srcs,
                                                         const int* __restrict__ rowptr,
                                                         const float* __restrict__ triplet_h,
                                                         const float* __restrict__ g,
                                                         const float* __restrict__ b,
                                                         float* __restrict__ x,
                                                         unsigned short* __restrict__ xn)
{
    const int node = blockIdx.x * 4 + (threadIdx.x >> 6);
    const int lane = threadIdx.x & 63;
    int beg = rowptr[node];
    int end = rowptr[node + 1];
    beg = max(0, min(beg, N_EDGES));
    end = max(beg, min(end, N_EDGES));
    const int deg = end - beg;

    const ushort4 ku = *reinterpret_cast<const ushort4*>(
        kbf + (size_t)node * 256 + lane * 4);
    const float k0 = bf2f(ku.x) * ATT_SCALE, k1 = bf2f(ku.y) * ATT_SCALE;
    const float k2 = bf2f(ku.z) * ATT_SCALE, k3 = bf2f(ku.w) * ATT_SCALE;

    float dsum = 0.0f;
    float4 acc = {0.0f, 0.0f, 0.0f, 0.0f};

    for (int base = 0; base < deg; base += 64) {
        const int cnt = min(64, deg - base);
        const int idx = base + lane;
        const int sv = (idx < deg) ? srcs[beg + idx] : 0;   // coalesced prefetch
        int j = 0;
        for (; j + 4 <= cnt; j += 4) {
            const int s0 = __builtin_amdgcn_readlane(sv, j);
            const int s1 = __builtin_amdgcn_readlane(sv, j + 1);
            const int s2 = __builtin_amdgcn_readlane(sv, j + 2);
            const int s3 = __builtin_amdgcn_readlane(sv, j + 3);
            const unsigned int qa = *reinterpret_cast<const unsigned int*>(qf8 + (size_t)s0 * 256 + lane * 4);
            const unsigned int qb = *reinterpret_cast<const unsigned int*>(qf8 + (size_t)s1 * 256 + lane * 4);
            const unsigned int qc = *reinterpret_cast<const unsigned int*>(qf8 + (size_t)s2 * 256 + lane * 4);
            const unsigned int qd = *reinterpret_cast<const unsigned int*>(qf8 + (size_t)s3 * 256 + lane * 4);
            const unsigned int va = *reinterpret_cast<const unsigned int*>(vf8 + (size_t)s0 * 256 + lane * 4);
            const unsigned int vb = *reinterpret_cast<const unsigned int*>(vf8 + (size_t)s1 * 256 + lane * 4);
            const unsigned int vc = *reinterpret_cast<const unsigned int*>(vf8 + (size_t)s2 * 256 + lane * 4);
            const unsigned int vd = *reinterpret_cast<const unsigned int*>(vf8 + (size_t)s3 * 256 + lane * 4);
            float a0, a1, a2, a3;
            dec4_e4m3(qa, a0, a1, a2, a3);
            float p0 = a0 * k0 + a1 * k1 + a2 * k2 + a3 * k3;
            dec4_e4m3(qb, a0, a1, a2, a3);
            float p1 = a0 * k0 + a1 * k1 + a2 * k2 + a3 * k3;
            dec4_e4m3(qc, a0, a1, a2, a3);
            float p2 = a0 * k0 + a1 * k1 + a2 * k2 + a3 * k3;
            dec4_e4m3(qd, a0, a1, a2, a3);
            float p3 = a0 * k0 + a1 * k1 + a2 * k2 + a3 * k3;
            p0 += __shfl_xor(p0, 1, 64); p1 += __shfl_xor(p1, 1, 64);
            p2 += __shfl_xor(p2, 1, 64); p3 += __shfl_xor(p3, 1, 64);
            p0 += __shfl_xor(p0, 2, 64); p1 += __shfl_xor(p1, 2, 64);
            p2 += __shfl_xor(p2, 2, 64); p3 += __shfl_xor(p3, 2, 64);
            p0 += __shfl_xor(p0, 4, 64); p1 += __shfl_xor(p1, 4, 64);
            p2 += __shfl_xor(p2, 4, 64); p3 += __shfl_xor(p3, 4, 64);
            const float w0 = __expf(p0), w1 = __expf(p1), w2 = __expf(p2), w3 = __expf(p3);
            float v0, v1, v2, v3;
            dec4_e4m3(va, v0, v1, v2, v3);
            acc.x += w0 * v0; acc.y += w0 * v1; acc.z += w0 * v2; acc.w += w0 * v3;
            dec4_e4m3(vb, v0, v1, v2, v3);
            acc.x += w1 * v0; acc.y += w1 * v1; acc.z += w1 * v2; acc.w += w1 * v3;
            dec4_e4m3(vc, v0, v1, v2, v3);
            acc.x += w2 * v0; acc.y += w2 * v1; acc.z += w2 * v2; acc.w += w2 * v3;
            dec4_e4m3(vd, v0, v1, v2, v3);
            acc.x += w3 * v0; acc.y += w3 * v1; acc.z += w3 * v2; acc.w += w3 * v3;
            dsum += (w0 + w1) + (w2 + w3);
        }
        for (; j < cnt; ++j) {
            const int s0 = __builtin_amdgcn_readlane(sv, j);
            const unsigned int qa = *reinterpret_cast<const unsigned int*>(qf8 + (size_t)s0 * 256 + lane * 4);
            const unsigned int va = *reinterpret_cast<const unsigned int*>(vf8 + (size_t)s0 * 256 + lane * 4);
            float a0, a1, a2, a3;
            dec4_e4m3(qa, a0, a1, a2, a3);
            float p0 = a0 * k0 + a1 * k1 + a2 * k2 + a3 * k3;
            p0 += __shfl_xor(p0, 1, 64);
            p0 += __shfl_xor(p0, 2, 64);
            p0 += __shfl_xor(p0, 4, 64);
            const float w0 = __expf(p0);
            float v0, v1, v2, v3;
            dec4_e4m3(va, v0, v1, v2, v3);
            acc.x += w0 * v0; acc.y += w0 * v1; acc.z += w0 * v2; acc.w += w0 * v3;
            dsum += w0;
        }
    }
    const float inv = (deg > 0) ? 1.0f / dsum : 0.0f;

    const float4 th = *reinterpret_cast<const float4*>(
        triplet_h + (size_t)node * D + lane * 4);
    float4 xv;
    xv.x = th.x + acc.x * inv;
    xv.y = th.y + acc.y * inv;
    xv.z = th.z + acc.z * inv;
    xv.w = th.w + acc.w * inv;
    *reinterpret_cast<float4*>(x + (size_t)node * D + lane * 4) = xv;

    // LN2 across the wave
    float s  = xv.x + xv.y + xv.z + xv.w;
    float s2 = xv.x * xv.x + xv.y * xv.y + xv.z * xv.z + xv.w * xv.w;
#pragma unroll
    for (int o = 32; o > 0; o >>= 1) {
        s  += __shfl_xor(s,  o, 64);
        s2 += __shfl_xor(s2, o, 64);
    }
    const float mu  = s * (1.0f / D);
    const float var = s2 * (1.0f / D) - mu * mu;
    const float rs  = rsqrtf(var + LN_EPS);
    const float4 gg = *reinterpret_cast<const float4*>(g + lane * 4);
    const float4 bb = *reinterpret_cast<const float4*>(b + lane * 4);
    ushort4 o4;
    o4.x = f2bf((xv.x - mu) * rs * gg.x + bb.x);
    o4.y = f2bf((xv.y - mu) * rs * gg.y + bb.y);
    o4.z = f2bf((xv.z - mu) * rs * gg.z + bb.z);
    o4.w = f2bf((xv.w - mu) * rs * gg.w + bb.w);
    const size_t off = (((size_t)(node >> 4) * (D / 8) + (lane >> 1)) * 16 + (node & 15)) * 8
                       + (lane & 1) * 4;
    *reinterpret_cast<ushort4*>(xn + off) = o4;
}

// ---------------------------------------------------------------------------
extern "C" void kernel_launch(void* const* d_in, const int* in_sizes, int n_in,
                              void* d_out, int out_size, void* d_ws, size_t ws_size,
                              hipStream_t stream)
{
    const float* triplet_h = (const float*)d_in[0];
    const int*   src       = (const int*)d_in[1];
    const int*   dst       = (const int*)d_in[2];
    const float* Wqkv      = (const float*)d_in[3];
    const float* bqkv      = (const float*)d_in[4];
    const float* ln_attn_g = (const float*)d_in[5];
    const float* ln_attn_b = (const float*)d_in[6];
    const float* ln_res_g  = (const float*)d_in[7];
    const float* ln_res_b  = (const float*)d_in[8];
    const float* W_in      = (const float*)d_in[9];
    const float* b_in      = (const float*)d_in[10];
    const float* W_out     = (const float*)d_in[11];
    const float* b_out     = (const float*)d_in[12];
    float* out = (float*)d_out;

    // Workspace (~95 MB):
    char* w = (char*)d_ws;
    unsigned short* h_xn = (unsigned short*)w;  w += (size_t)M_PAD * D * sizeof(unsigned short);
    unsigned short* kbf  = (unsigned short*)w;  w += (size_t)N_NODES * D * sizeof(unsigned short);
    float*          x    = (float*)w;           w += (size_t)N_NODES * D * sizeof(float);
    unsigned char*  qf8  = (unsigned char*)w;   w += (size_t)N_NODES * 256;
    unsigned char*  vf8  = (unsigned char*)w;   w += (size_t)N_NODES * 256;
    unsigned short* Wqkv_pk = (unsigned short*)w; w += (size_t)D * D3 * sizeof(unsigned short);
    unsigned short* Win_pk  = (unsigned short*)w; w += (size_t)D * DFF * sizeof(unsigned short);
    unsigned short* Wout_pk = (unsigned short*)w; w += (size_t)DFF * D * sizeof(unsigned short);
    int* counts = (int*)w;  w += (size_t)N_NODES * sizeof(int);
    int* rowptr = (int*)w;  w += (size_t)(N_NODES + 1) * sizeof(int);
    int* cursor = (int*)w;  w += (size_t)N_NODES * sizeof(int);
    int* srcs   = (int*)w;  w += (size_t)N_EDGES * sizeof(int);

    // ---- CSR build ----
    (void)hipMemsetAsync(counts, 0, (size_t)N_NODES * sizeof(int), stream);
    hist_kernel<<<N_EDGES / 256, 256, 0, stream>>>(dst, counts);
    scan_kernel<<<1, 1024, 0, stream>>>(counts, rowptr, cursor);
    fill_kernel<<<N_EDGES / 256, 256, 0, stream>>>(src, dst, cursor, srcs);

    // ---- weight packing (one launch) ----
    pack_all_kernel<<<352, 256, 0, stream>>>(Wqkv, W_in, W_out, Wqkv_pk, Win_pk, Wout_pk);

    // ---- main pipeline ----
    ln_bf_kernel<<<M_PAD / 4, 256, 0, stream>>>(triplet_h, ln_attn_g, ln_attn_b, h_xn);
    mfma_gemm_kernel<0, D, D3><<<((M_PAD / 128 + 7) / 8) * 8 * (D3 / 128), 256, 0, stream>>>(
        h_xn, Wqkv_pk, bqkv, qf8, kbf, vf8);
    fused_attn_kernel<<<N_NODES / 4, 256, 0, stream>>>(qf8, kbf, vf8, srcs, rowptr, triplet_h,
                                                       ln_res_g, ln_res_b, x, h_xn);
    fused_ffn_kernel<<<M_PAD / 64, 256, 0, stream>>>(h_xn, Win_pk, Wout_pk, b_in, b_out, x, out);

    (void)in_sizes; (void)n_in; (void)out_size; (void)ws_size;
}

// Round 10
// 547.337 us; speedup vs baseline: 1.2932x; 1.2932x over previous
//
#include <hip/hip_runtime.h>
#include <math.h>

#define N_NODES 40000
#define M_PAD   40064      // 313 * 128
#define N_EDGES 640000
#define D       256
#define H       8
#define DFF     1024
#define D3      768
#define ATT_SCALE 0.0625f  // 256^-0.5
#define LN_EPS  1e-5f

typedef __attribute__((ext_vector_type(8))) short short8;
typedef __attribute__((ext_vector_type(4))) float f32x4;
typedef __attribute__((ext_vector_type(2))) float f32x2;

__device__ __forceinline__ unsigned short f2bf(float f) {
    unsigned int u = __builtin_bit_cast(unsigned int, f);
    u = (u + 0x7FFF + ((u >> 16) & 1)) >> 16;   // RTNE
    return (unsigned short)u;
}
__device__ __forceinline__ float bf2f(unsigned short u) {
    return __builtin_bit_cast(float, (unsigned int)u << 16);
}

// Fast exact-gelu: Abramowitz-Stegun 7.1.26 erf (|eps| <= 1.5e-7, branchless).
__device__ __forceinline__ float fast_gelu(float x) {
    const float z  = fabsf(x) * 0.70710678118654752f;
    const float t  = __builtin_amdgcn_rcpf(1.0f + 0.3275911f * z);
    float p = 1.061405429f;
    p = p * t - 1.453152027f;
    p = p * t + 1.421413741f;
    p = p * t - 0.284496736f;
    p = p * t + 0.254829592f;
    const float e  = __expf(-z * z);
    const float ea = 1.0f - p * t * e;          // erf(|x|/sqrt2)
    const float er = (x < 0.0f) ? -ea : ea;
    return 0.5f * x * (1.0f + er);
}

#define GLOAD_LDS16(g, l) \
    __builtin_amdgcn_global_load_lds((const __attribute__((address_space(1))) void*)(g), \
                                     (__attribute__((address_space(3))) void*)(l), 16, 0, 0)

// ---------------- fp8 e4m3 pack/unpack (HW cvt on gfx950, SW fallback) -----
#if __has_builtin(__builtin_amdgcn_cvt_pk_fp8_f32) && __has_builtin(__builtin_amdgcn_cvt_pk_f32_fp8)
#define HW_FP8 1
#else
#define HW_FP8 0
__device__ __forceinline__ unsigned char enc_e4m3(float f) {
    unsigned int u = __builtin_bit_cast(unsigned int, f);
    unsigned int s = (u >> 24) & 0x80;
    float a = fabsf(f);
    if (a >= 0x1p-6f) {
        unsigned int bits = __builtin_bit_cast(unsigned int, a);
        unsigned int q = bits >> 20;
        unsigned int rem = bits & 0xFFFFFu;
        q += (rem > 0x80000u) || ((rem == 0x80000u) && (q & 1));
        q -= 960;                          // rebias (120<<3)
        if (q > 126) q = 126;              // clamp to 448
        return (unsigned char)(s | q);
    }
    float t = a * 512.0f;
    unsigned int r = (unsigned int)rintf(t);   // RNE; 8 -> min normal naturally
    return (unsigned char)(s | r);
}
__device__ __forceinline__ float dec_e4m3(unsigned int v) {
    unsigned int em = v & 0x7f;
    float n = __builtin_bit_cast(float, (em << 20) + 0x3C000000u);
    float r = (em >= 8) ? n : (float)em * 0x1p-9f;
    return (v & 0x80) ? -r : r;
}
#endif

__device__ __forceinline__ unsigned int pack4_e4m3(float a, float b, float c, float d) {
#if HW_FP8
    unsigned int w = (unsigned int)__builtin_amdgcn_cvt_pk_fp8_f32(a, b, 0, false);
    w = (unsigned int)__builtin_amdgcn_cvt_pk_fp8_f32(c, d, (int)w, true);
    return w;
#else
    return (unsigned int)enc_e4m3(a) | ((unsigned int)enc_e4m3(b) << 8)
         | ((unsigned int)enc_e4m3(c) << 16) | ((unsigned int)enc_e4m3(d) << 24);
#endif
}
__device__ __forceinline__ void dec4_e4m3(unsigned int w, float& a, float& b, float& c, float& d) {
#if HW_FP8
    f32x2 lo = __builtin_amdgcn_cvt_pk_f32_fp8((int)w, false);
    f32x2 hi = __builtin_amdgcn_cvt_pk_f32_fp8((int)w, true);
    a = lo[0]; b = lo[1]; c = hi[0]; d = hi[1];
#else
    a = dec_e4m3(w & 0xff); b = dec_e4m3((w >> 8) & 0xff);
    c = dec_e4m3((w >> 16) & 0xff); d = dec_e4m3(w >> 24);
#endif
}

// ---------------------------------------------------------------------------
// LayerNorm -> bf16 output in MFMA A-fragment order [M/16][D/8][16][8].
// Covers pad rows [N_NODES, M_PAD) with zeros (replaces a memset).
// ---------------------------------------------------------------------------
__global__ __launch_bounds__(256) void ln_bf_kernel(const float* __restrict__ in,
                                                    const float* __restrict__ g,
                                                    const float* __restrict__ b,
                                                    unsigned short* __restrict__ out)
{
    const int row  = blockIdx.x * 4 + (threadIdx.x >> 6);
    const int lane = threadIdx.x & 63;
    const size_t off = (((size_t)(row >> 4) * (D / 8) + (lane >> 1)) * 16 + (row & 15)) * 8
                       + (lane & 1) * 4;
    if (row >= N_NODES) {
        ushort4 z = {0, 0, 0, 0};
        *reinterpret_cast<ushort4*>(out + off) = z;
        return;
    }
    const float4 v = *reinterpret_cast<const float4*>(in + (size_t)row * D + lane * 4);
    float s  = v.x + v.y + v.z + v.w;
    float s2 = v.x * v.x + v.y * v.y + v.z * v.z + v.w * v.w;
#pragma unroll
    for (int o = 32; o > 0; o >>= 1) {
        s  += __shfl_xor(s,  o, 64);
        s2 += __shfl_xor(s2, o, 64);
    }
    const float mu  = s * (1.0f / D);
    const float var = s2 * (1.0f / D) - mu * mu;
    const float rs  = rsqrtf(var + LN_EPS);
    const float4 gg = *reinterpret_cast<const float4*>(g + lane * 4);
    const float4 bb = *reinterpret_cast<const float4*>(b + lane * 4);
    ushort4 o4;
    o4.x = f2bf((v.x - mu) * rs * gg.x + bb.x);
    o4.y = f2bf((v.y - mu) * rs * gg.y + bb.y);
    o4.z = f2bf((v.z - mu) * rs * gg.z + bb.z);
    o4.w = f2bf((v.w - mu) * rs * gg.w + bb.w);
    *reinterpret_cast<ushort4*>(out + off) = o4;
}

// ---------------------------------------------------------------------------
// Weight pack: W[K][N] fp32 -> bf16 packed [N/16][K/8][16][8]. All three
// weights in ONE kernel (one launch).
// ---------------------------------------------------------------------------
template <int K, int N>
__device__ __forceinline__ void pack_body(const float* __restrict__ W,
                                          unsigned short* __restrict__ Wpk, int blk)
{
    const int idx = blk * 256 + threadIdx.x;   // [N/16][K/8][16]
    const int ni  = idx & 15;
    const int kc  = (idx >> 4) % (K / 8);
    const int nt  = idx / (16 * (K / 8));
    const int n   = nt * 16 + ni;
    unsigned short o[8];
#pragma unroll
    for (int i = 0; i < 8; ++i)
        o[i] = f2bf(W[(size_t)(kc * 8 + i) * N + n]);
    *reinterpret_cast<short8*>(Wpk + (size_t)idx * 8) = *reinterpret_cast<short8*>(o);
}

__global__ __launch_bounds__(256) void pack_all_kernel(const float* __restrict__ Wqkv,
                                                       const float* __restrict__ W_in,
                                                       const float* __restrict__ W_out,
                                                       unsigned short* __restrict__ pq,
                                                       unsigned short* __restrict__ pi,
                                                       unsigned short* __restrict__ po)
{
    const int b = blockIdx.x;
    if (b < 96)       pack_body<D, D3 >(Wqkv, pq, b);
    else if (b < 224) pack_body<D, DFF>(W_in, pi, b - 96);
    else              pack_body<DFF, D>(W_out, po, b - 224);
}

// ---------------------------------------------------------------------------
// bf16 MFMA GEMM (qkv only) -- m97 staging structure, 128x128 tile,
// 4 waves, BK=32, global_load_lds width 16, LDS 16 KB, 4 blocks/CU.
// Panel-colocating XCD swizzle. MFMA operands SWAPPED: D maps to row
// r = lane&15, cols n = (lane>>4)*4+t -> 4 consecutive cols per thread.
// EPI: qkv 3-way split -> q fp8 (unscaled), k bf16 [node][256], v fp8
// ---------------------------------------------------------------------------
template <int EPI, int K, int N>
__global__ __launch_bounds__(256, 4) void mfma_gemm_kernel(const unsigned short* __restrict__ A,
                                                           const unsigned short* __restrict__ Bpk,
                                                           const float* __restrict__ bias,
                                                           void* __restrict__ Cout,
                                                           void* __restrict__ Cout2,
                                                           void* __restrict__ Cout3)
{
    constexpr int C = N / 128;           // col tiles
    constexpr int P = M_PAD / 128;       // 313 row panels

    const int bid = blockIdx.x;
    const int xcd = bid & 7;
    const int t   = bid >> 3;
    const int c   = t % C;
    const int p   = (t / C) * 8 + xcd;
    if (p >= P) return;

    __shared__ unsigned short As[4096];   // [mt8][16][8] = 8 KB
    __shared__ unsigned short Bs[4096];

    const int tid  = threadIdx.x;
    const int wave = tid >> 6;
    const int lane = tid & 63;
    const int row0 = p * 128;
    const int col0 = c * 128;
    const int wm   = (wave >> 1) * 64;
    const int wn   = (wave & 1) * 64;
    const int g    = lane >> 4;
    const int q    = lane & 15;

    f32x4 acc[4][4] = {};

    const int fragoff = g * 128 + q * 8;

    for (int k0 = 0; k0 < K; k0 += 32) {
        const int kq = k0 >> 3;   // k-chunk index (K/8 units)
#pragma unroll
        for (int cc = 0; cc < 2; ++cc) {
            const int mt = wave * 2 + cc;                // 0..7
            const unsigned short* gA =
                A + ((size_t)(row0 / 16 + mt) * (K / 8) + kq) * 128 + lane * 8;
            GLOAD_LDS16(gA, &As[mt * 512]);
            const unsigned short* gB =
                Bpk + ((size_t)(col0 / 16 + mt) * (K / 8) + kq) * 128 + lane * 8;
            GLOAD_LDS16(gB, &Bs[mt * 512]);
        }
        __syncthreads();

        short8 af[4], bf[4];
#pragma unroll
        for (int i = 0; i < 4; ++i) {
            af[i] = *reinterpret_cast<const short8*>(&As[(wm / 16 + i) * 512 + fragoff]);
            bf[i] = *reinterpret_cast<const short8*>(&Bs[(wn / 16 + i) * 512 + fragoff]);
        }
#pragma unroll
        for (int i = 0; i < 4; ++i)
#pragma unroll
            for (int j = 0; j < 4; ++j)
                acc[i][j] = __builtin_amdgcn_mfma_f32_16x16x32_bf16(bf[j], af[i], acc[i][j], 0, 0, 0);
        __syncthreads();
    }

    // Swapped D layout: r = row0+wm+i*16+q ; n = col0+wn+j*16+g*4+t (t=0..3)
    if (col0 < 256) {        // q cols -> fp8, UNSCALED (scale folded into k)
        unsigned char* q8 = (unsigned char*)Cout;
#pragma unroll
        for (int j = 0; j < 4; ++j) {
            const int nb = col0 + wn + j * 16 + g * 4;
            const float4 bz = *reinterpret_cast<const float4*>(bias + nb);
#pragma unroll
            for (int i = 0; i < 4; ++i) {
                const int r = row0 + wm + i * 16 + q;
                if (r >= N_NODES) continue;
                const unsigned int w = pack4_e4m3(acc[i][j][0] + bz.x, acc[i][j][1] + bz.y,
                                                  acc[i][j][2] + bz.z, acc[i][j][3] + bz.w);
                *reinterpret_cast<unsigned int*>(q8 + (size_t)r * 256 + nb) = w;
            }
        }
    } else if (col0 < 512) { // k cols -> bf16 row-major [node][256]
        unsigned short* kb = (unsigned short*)Cout2;
#pragma unroll
        for (int j = 0; j < 4; ++j) {
            const int nb = col0 + wn + j * 16 + g * 4;
            const float4 bz = *reinterpret_cast<const float4*>(bias + nb);
#pragma unroll
            for (int i = 0; i < 4; ++i) {
                const int r = row0 + wm + i * 16 + q;
                if (r >= N_NODES) continue;
                ushort4 u;
                u.x = f2bf(acc[i][j][0] + bz.x);
                u.y = f2bf(acc[i][j][1] + bz.y);
                u.z = f2bf(acc[i][j][2] + bz.z);
                u.w = f2bf(acc[i][j][3] + bz.w);
                *reinterpret_cast<ushort4*>(kb + (size_t)r * 256 + (nb - 256)) = u;
            }
        }
    } else {                 // v cols -> fp8 [node][256]
        unsigned char* v8 = (unsigned char*)Cout3;
#pragma unroll
        for (int j = 0; j < 4; ++j) {
            const int nb = col0 + wn + j * 16 + g * 4;
            const float4 bz = *reinterpret_cast<const float4*>(bias + nb);
#pragma unroll
            for (int i = 0; i < 4; ++i) {
                const int r = row0 + wm + i * 16 + q;
                if (r >= N_NODES) continue;
                const unsigned int w = pack4_e4m3(acc[i][j][0] + bz.x, acc[i][j][1] + bz.y,
                                                  acc[i][j][2] + bz.z, acc[i][j][3] + bz.w);
                *reinterpret_cast<unsigned int*>(v8 + (size_t)r * 256 + (nb - 512)) = w;
            }
        }
    }
}

// ---------------------------------------------------------------------------
// Fused FFN v2: out = x + gelu(xn @ W_in + b_in) @ W_out + b_out.
// SPILL FIX vs v1: 512 threads (8 waves) per 64-row panel halves per-thread
// accumulator state (v1: acc2=64+acc1=32+ops > 170-reg cap -> 1.3 GB scratch
// traffic, 472 us). Per wave now: rows 32, GEMM1 cols 32 (acc1[2][2]=16),
// GEMM2 cols 64 (acc2[2][4]=32); peak ~100 regs < 128 cap of (512,4).
// Loops DFF in 8 chunks of 128: GEMM1 chunk -> gelu -> 16 KB LDS tile in
// GEMM2-A fragment order -> GEMM2 accumulate into persistent 64x256 acc.
// ---------------------------------------------------------------------------
__global__ __launch_bounds__(512, 4) void fused_ffn_kernel(const unsigned short* __restrict__ A,
                                                           const unsigned short* __restrict__ Wi,
                                                           const unsigned short* __restrict__ Wo,
                                                           const float* __restrict__ b_in,
                                                           const float* __restrict__ b_out,
                                                           const float* __restrict__ x,
                                                           float* __restrict__ out)
{
    __shared__ unsigned short a1c[8192];   // [mt4][kc16][16][8] = 16 KB

    const int p    = blockIdx.x;           // 64-row panel, 0..625
    const int tid  = threadIdx.x;
    const int wave = tid >> 6;             // 0..7
    const int lane = tid & 63;
    const int g    = lane >> 4;
    const int q    = lane & 15;
    const int wrow = (wave & 1) * 2;       // row mt offset (rows (wave&1)*32..+31)
    const int cg   = wave >> 1;            // col group 0..3
    const int wc1  = cg * 2;               // GEMM1: 2 nt (32 cols) per wave
    const int wc2  = cg * 4;               // GEMM2: 4 nt (64 cols) per wave

    f32x4 acc2[2][4] = {};

#pragma unroll 1
    for (int ch = 0; ch < 8; ++ch) {
        // ---- GEMM1 chunk: a1[64][128] = xn[64][256] @ W_in[:, ch*128..+127]
        f32x4 acc1[2][2] = {};
#pragma unroll
        for (int ks = 0; ks < 8; ++ks) {
            const int kc = ks * 4 + g;     // K/8 index, 0..31
            short8 ah[2], bw[2];
#pragma unroll
            for (int i = 0; i < 2; ++i)
                ah[i] = *reinterpret_cast<const short8*>(
                    A + ((size_t)(p * 4 + wrow + i) * 32 + kc) * 128 + q * 8);
#pragma unroll
            for (int j = 0; j < 2; ++j) {
                const int nt = ch * 8 + wc1 + j;   // DFF/16 index
                bw[j] = *reinterpret_cast<const short8*>(
                    Wi + ((size_t)nt * 32 + kc) * 128 + q * 8);
            }
#pragma unroll
            for (int i = 0; i < 2; ++i)
#pragma unroll
                for (int j = 0; j < 2; ++j)
                    acc1[i][j] = __builtin_amdgcn_mfma_f32_16x16x32_bf16(bw[j], ah[i], acc1[i][j], 0, 0, 0);
        }
        __syncthreads();   // prev chunk's GEMM2 reads of a1c complete

        // ---- gelu + pack to LDS in GEMM2-A fragment order
#pragma unroll
        for (int j = 0; j < 2; ++j) {
            const int cb = (wc1 + j) * 16 + g * 4;       // chunk-local col 0..127
            const float4 bz = *reinterpret_cast<const float4*>(b_in + ch * 128 + cb);
            const int kc = cb >> 3;
            const int ki = cb & 7;
#pragma unroll
            for (int i = 0; i < 2; ++i) {
                ushort4 u;
                u.x = f2bf(fast_gelu(acc1[i][j][0] + bz.x));
                u.y = f2bf(fast_gelu(acc1[i][j][1] + bz.y));
                u.z = f2bf(fast_gelu(acc1[i][j][2] + bz.z));
                u.w = f2bf(fast_gelu(acc1[i][j][3] + bz.w));
                *reinterpret_cast<ushort4*>(
                    &a1c[(((wrow + i) * 16 + kc) * 16 + q) * 8 + ki]) = u;
            }
        }
        __syncthreads();   // a1c visible

        // ---- GEMM2 accumulate: acc2 += a1[64][128] @ W_out[ch*128..+127][:]
#pragma unroll
        for (int ks = 0; ks < 4; ++ks) {
            const int kc = ks * 4 + g;     // chunk-local K/8, 0..15
            short8 aa[2], bw2[4];
#pragma unroll
            for (int i = 0; i < 2; ++i)
                aa[i] = *reinterpret_cast<const short8*>(
                    &a1c[(((wrow + i) * 16 + kc) * 16 + q) * 8]);
#pragma unroll
            for (int j = 0; j < 4; ++j) {
                const int nt  = wc2 + j;                // 0..15 (N=256)
                const int kcg = ch * 16 + kc;           // global K/8 of DFF
                bw2[j] = *reinterpret_cast<const short8*>(
                    Wo + ((size_t)nt * 128 + kcg) * 128 + q * 8);
            }
#pragma unroll
            for (int i = 0; i < 2; ++i)
#pragma unroll
                for (int j = 0; j < 4; ++j)
                    acc2[i][j] = __builtin_amdgcn_mfma_f32_16x16x32_bf16(bw2[j], aa[i], acc2[i][j], 0, 0, 0);
        }
    }

    // ---- epilogue: out = acc2 + b_out + x (rows r = p*64 + (wrow+i)*16 + q)
#pragma unroll
    for (int j = 0; j < 4; ++j) {
        const int col = (wc2 + j) * 16 + g * 4;
        const float4 bz = *reinterpret_cast<const float4*>(b_out + col);
#pragma unroll
        for (int i = 0; i < 2; ++i) {
            const int r = p * 64 + (wrow + i) * 16 + q;
            if (r >= N_NODES) continue;
            const f32x4 xd = __builtin_nontemporal_load(
                reinterpret_cast<const f32x4*>(x + (size_t)r * D + col));
            f32x4 ov;
            ov[0] = acc2[i][j][0] + bz.x + xd[0];
            ov[1] = acc2[i][j][1] + bz.y + xd[1];
            ov[2] = acc2[i][j][2] + bz.z + xd[2];
            ov[3] = acc2[i][j][3] + bz.w + xd[3];
            __builtin_nontemporal_store(ov,
                reinterpret_cast<f32x4*>(out + (size_t)r * D + col));
        }
    }
}

// ---------------------------------------------------------------------------
// CSR build
// ---------------------------------------------------------------------------
__global__ __launch_bounds__(256) void hist_kernel(const int* __restrict__ dst,
                                                   int* __restrict__ counts)
{
    const int i = blockIdx.x * 256 + threadIdx.x;
    atomicAdd(&counts[dst[i]], 1);
}

// Two-pass, ARRAY-FREE scan (int c[40] spilled to scratch -> was 64 us).
__global__ __launch_bounds__(1024) void scan_kernel(const int* __restrict__ counts,
                                                    int* __restrict__ rowptr,
                                                    int* __restrict__ cursor)
{
    const int PER = 40;
    const int tid  = threadIdx.x;
    const int base = tid * PER;
    const bool act = (base < N_NODES);     // threads 0..999 own 40 each
    int s = 0;
    if (act) {
#pragma unroll
        for (int i = 0; i < PER / 4; ++i) {
            const int4 c4 = *reinterpret_cast<const int4*>(counts + base + i * 4);
            s += (c4.x + c4.y) + (c4.z + c4.w);
        }
    }
    __shared__ int sm[1024];
    sm[tid] = s;
    __syncthreads();
    for (int off = 1; off < 1024; off <<= 1) {
        int t = (tid >= off) ? sm[tid - off] : 0;
        __syncthreads();
        sm[tid] += t;
        __syncthreads();
    }
    int run = sm[tid] - s;                 // exclusive prefix of this chunk
    if (act) {
#pragma unroll
        for (int i = 0; i < PER / 4; ++i) {
            const int4 c4 = *reinterpret_cast<const int4*>(counts + base + i * 4);
            int4 r4;
            r4.x = run;
            r4.y = r4.x + c4.x;
            r4.z = r4.y + c4.y;
            r4.w = r4.z + c4.z;
            run  = r4.w + c4.w;
            *reinterpret_cast<int4*>(rowptr + base + i * 4) = r4;
            *reinterpret_cast<int4*>(cursor + base + i * 4) = r4;
        }
    }
    if (tid == 1023) rowptr[N_NODES] = sm[1023];
}

__global__ __launch_bounds__(256) void fill_kernel(const int* __restrict__ src,
                                                   const int* __restrict__ dst,
                                                   int* __restrict__ cursor,
                                                   int* __restrict__ srcs)
{
    const int e = blockIdx.x * 256 + threadIdx.x;
    const int pos = atomicAdd(&cursor[dst[e]], 1);
    if (pos >= 0 && pos < N_EDGES) srcs[pos] = src[e];
}

// ---------------------------------------------------------------------------
// Fused attention: q fp8 (256 B/row, gathered) + v fp8 (256 B/row, gathered)
// + k bf16 (512 B/row, loaded once per dst node). Edge gather = 512 B.
// One wave per dst node; src list coalesce-prefetched, readlane broadcast,
// 4-edge unroll. k scaled by ATT_SCALE at load.
// Outputs: x fp32 row-major, xn bf16 in fragment order.
// ---------------------------------------------------------------------------
__global__ __launch_bounds__(256) void fused_attn_kernel(const unsigned char* __restrict__ qf8,
                                                         const unsigned short* __restrict__ kbf,
                                                         const unsigned char* __restrict__ vf8,
                                                         const int* __restrict__ srcs,
                                                         const int* __restrict__ rowptr,
                                                         const float* __restrict__ triplet_h,
                                                         const float* __restrict__ g,
                                                         const float* __restrict__ b,
                                                         float* __restrict__ x,
                                                         unsigned short* __restrict__ xn)
{
    const int node = blockIdx.x * 4 + (threadIdx.x >> 6);
    const int lane = threadIdx.x & 63;
    int beg = rowptr[node];
    int end = rowptr[node + 1];
    beg = max(0, min(beg, N_EDGES));
    end = max(beg, min(end, N_EDGES));
    const int deg = end - beg;

    const ushort4 ku = *reinterpret_cast<const ushort4*>(
        kbf + (size_t)node * 256 + lane * 4);
    const float k0 = bf2f(ku.x) * ATT_SCALE, k1 = bf2f(ku.y) * ATT_SCALE;
    const float k2 = bf2f(ku.z) * ATT_SCALE, k3 = bf2f(ku.w) * ATT_SCALE;

    float dsum = 0.0f;
    float4 acc = {0.0f, 0.0f, 0.0f, 0.0f};

    for (int base = 0; base < deg; base += 64) {
        const int cnt = min(64, deg - base);
        const int idx = base + lane;
        const int sv = (idx < deg) ? srcs[beg + idx] : 0;   // coalesced prefetch
        int j = 0;
        for (; j + 4 <= cnt; j += 4) {
            const int s0 = __builtin_amdgcn_readlane(sv, j);
            const int s1 = __builtin_amdgcn_readlane(sv, j + 1);
            const int s2 = __builtin_amdgcn_readlane(sv, j + 2);
            const int s3 = __builtin_amdgcn_readlane(sv, j + 3);
            const unsigned int qa = *reinterpret_cast<const unsigned int*>(qf8 + (size_t)s0 * 256 + lane * 4);
            const unsigned int qb = *reinterpret_cast<const unsigned int*>(qf8 + (size_t)s1 * 256 + lane * 4);
            const unsigned int qc = *reinterpret_cast<const unsigned int*>(qf8 + (size_t)s2 * 256 + lane * 4);
            const unsigned int qd = *reinterpret_cast<const unsigned int*>(qf8 + (size_t)s3 * 256 + lane * 4);
            const unsigned int va = *reinterpret_cast<const unsigned int*>(vf8 + (size_t)s0 * 256 + lane * 4);
            const unsigned int vb = *reinterpret_cast<const unsigned int*>(vf8 + (size_t)s1 * 256 + lane * 4);
            const unsigned int vc = *reinterpret_cast<const unsigned int*>(vf8 + (size_t)s2 * 256 + lane * 4);
            const unsigned int vd = *reinterpret_cast<const unsigned int*>(vf8 + (size_t)s3 * 256 + lane * 4);
            float a0, a1, a2, a3;
            dec4_e4m3(qa, a0, a1, a2, a3);
            float p0 = a0 * k0 + a1 * k1 + a2 * k2 + a3 * k3;
            dec4_e4m3(qb, a0, a1, a2, a3);
            float p1 = a0 * k0 + a1 * k1 + a2 * k2 + a3 * k3;
            dec4_e4m3(qc, a0, a1, a2, a3);
            float p2 = a0 * k0 + a1 * k1 + a2 * k2 + a3 * k3;
            dec4_e4m3(qd, a0, a1, a2, a3);
            float p3 = a0 * k0 + a1 * k1 + a2 * k2 + a3 * k3;
            p0 += __shfl_xor(p0, 1, 64); p1 += __shfl_xor(p1, 1, 64);
            p2 += __shfl_xor(p2, 1, 64); p3 += __shfl_xor(p3, 1, 64);
            p0 += __shfl_xor(p0, 2, 64); p1 += __shfl_xor(p1, 2, 64);
            p2 += __shfl_xor(p2, 2, 64); p3 += __shfl_xor(p3, 2, 64);
            p0 += __shfl_xor(p0, 4, 64); p1 += __shfl_xor(p1, 4, 64);
            p2 += __shfl_xor(p2, 4, 64); p3 += __shfl_xor(p3, 4, 64);
            const float w0 = __expf(p0), w1 = __expf(p1), w2 = __expf(p2), w3 = __expf(p3);
            float v0, v1, v2, v3;
            dec4_e4m3(va, v0, v1, v2, v3);
            acc.x += w0 * v0; acc.y += w0 * v1; acc.z += w0 * v2; acc.w += w0 * v3;
            dec4_e4m3(vb, v0, v1, v2, v3);
            acc.x += w1 * v0; acc.y += w1 * v1; acc.z += w1 * v2; acc.w += w1 * v3;
            dec4_e4m3(vc, v0, v1, v2, v3);
            acc.x += w2 * v0; acc.y += w2 * v1; acc.z += w2 * v2; acc.w += w2 * v3;
            dec4_e4m3(vd, v0, v1, v2, v3);
            acc.x += w3 * v0; acc.y += w3 * v1; acc.z += w3 * v2; acc.w += w3 * v3;
            dsum += (w0 + w1) + (w2 + w3);
        }
        for (; j < cnt; ++j) {
            const int s0 = __builtin_amdgcn_readlane(sv, j);
            const unsigned int qa = *reinterpret_cast<const unsigned int*>(qf8 + (size_t)s0 * 256 + lane * 4);
            const unsigned int va = *reinterpret_cast<const unsigned int*>(vf8 + (size_t)s0 * 256 + lane * 4);
            float a0, a1, a2, a3;
            dec4_e4m3(qa, a0, a1, a2, a3);
            float p0 = a0 * k0 + a1 * k1 + a2 * k2 + a3 * k3;
            p0 += __shfl_xor(p0, 1, 64);
            p0 += __shfl_xor(p0, 2, 64);
            p0 += __shfl_xor(p0, 4, 64);
            const float w0 = __expf(p0);
            float v0, v1, v2, v3;
            dec4_e4m3(va, v0, v1, v2, v3);
            acc.x += w0 * v0; acc.y += w0 * v1; acc.z += w0 * v2; acc.w += w0 * v3;
            dsum += w0;
        }
    }
    const float inv = (deg > 0) ? 1.0f / dsum : 0.0f;

    const float4 th = *reinterpret_cast<const float4*>(
        triplet_h + (size_t)node * D + lane * 4);
    float4 xv;
    xv.x = th.x + acc.x * inv;
    xv.y = th.y + acc.y * inv;
    xv.z = th.z + acc.z * inv;
    xv.w = th.w + acc.w * inv;
    *reinterpret_cast<float4*>(x + (size_t)node * D + lane * 4) = xv;

    // LN2 across the wave
    float s  = xv.x + xv.y + xv.z + xv.w;
    float s2 = xv.x * xv.x + xv.y * xv.y + xv.z * xv.z + xv.w * xv.w;
#pragma unroll
    for (int o = 32; o > 0; o >>= 1) {
        s  += __shfl_xor(s,  o, 64);
        s2 += __shfl_xor(s2, o, 64);
    }
    const float mu  = s * (1.0f / D);
    const float var = s2 * (1.0f / D) - mu * mu;
    const float rs  = rsqrtf(var + LN_EPS);
    const float4 gg = *reinterpret_cast<const float4*>(g + lane * 4);
    const float4 bb = *reinterpret_cast<const float4*>(b + lane * 4);
    ushort4 o4;
    o4.x = f2bf((xv.x - mu) * rs * gg.x + bb.x);
    o4.y = f2bf((xv.y - mu) * rs * gg.y + bb.y);
    o4.z = f2bf((xv.z - mu) * rs * gg.z + bb.z);
    o4.w = f2bf((xv.w - mu) * rs * gg.w + bb.w);
    const size_t off = (((size_t)(node >> 4) * (D / 8) + (lane >> 1)) * 16 + (node & 15)) * 8
                       + (lane & 1) * 4;
    *reinterpret_cast<ushort4*>(xn + off) = o4;
}

// ---------------------------------------------------------------------------
extern "C" void kernel_launch(void* const* d_in, const int* in_sizes, int n_in,
                              void* d_out, int out_size, void* d_ws, size_t ws_size,
                              hipStream_t stream)
{
    const float* triplet_h = (const float*)d_in[0];
    const int*   src       = (const int*)d_in[1];
    const int*   dst       = (const int*)d_in[2];
    const float* Wqkv      = (const float*)d_in[3];
    const float* bqkv      = (const float*)d_in[4];
    const float* ln_attn_g = (const float*)d_in[5];
    const float* ln_attn_b = (const float*)d_in[6];
    const float* ln_res_g  = (const float*)d_in[7];
    const float* ln_res_b  = (const float*)d_in[8];
    const float* W_in      = (const float*)d_in[9];
    const float* b_in      = (const float*)d_in[10];
    const float* W_out     = (const float*)d_in[11];
    const float* b_out     = (const float*)d_in[12];
    float* out = (float*)d_out;

    // Workspace (~95 MB):
    char* w = (char*)d_ws;
    unsigned short* h_xn = (unsigned short*)w;  w += (size_t)M_PAD * D * sizeof(unsigned short);
    unsigned short* kbf  = (unsigned short*)w;  w += (size_t)N_NODES * D * sizeof(unsigned short);
    float*          x    = (float*)w;           w += (size_t)N_NODES * D * sizeof(float);
    unsigned char*  qf8  = (unsigned char*)w;   w += (size_t)N_NODES * 256;
    unsigned char*  vf8  = (unsigned char*)w;   w += (size_t)N_NODES * 256;
    unsigned short* Wqkv_pk = (unsigned short*)w; w += (size_t)D * D3 * sizeof(unsigned short);
    unsigned short* Win_pk  = (unsigned short*)w; w += (size_t)D * DFF * sizeof(unsigned short);
    unsigned short* Wout_pk = (unsigned short*)w; w += (size_t)DFF * D * sizeof(unsigned short);
    int* counts = (int*)w;  w += (size_t)N_NODES * sizeof(int);
    int* rowptr = (int*)w;  w += (size_t)(N_NODES + 1) * sizeof(int);
    int* cursor = (int*)w;  w += (size_t)N_NODES * sizeof(int);
    int* srcs   = (int*)w;  w += (size_t)N_EDGES * sizeof(int);

    // ---- CSR build ----
    (void)hipMemsetAsync(counts, 0, (size_t)N_NODES * sizeof(int), stream);
    hist_kernel<<<N_EDGES / 256, 256, 0, stream>>>(dst, counts);
    scan_kernel<<<1, 1024, 0, stream>>>(counts, rowptr, cursor);
    fill_kernel<<<N_EDGES / 256, 256, 0, stream>>>(src, dst, cursor, srcs);

    // ---- weight packing (one launch) ----
    pack_all_kernel<<<352, 256, 0, stream>>>(Wqkv, W_in, W_out, Wqkv_pk, Win_pk, Wout_pk);

    // ---- main pipeline ----
    ln_bf_kernel<<<M_PAD / 4, 256, 0, stream>>>(triplet_h, ln_attn_g, ln_attn_b, h_xn);
    mfma_gemm_kernel<0, D, D3><<<((M_PAD / 128 + 7) / 8) * 8 * (D3 / 128), 256, 0, stream>>>(
        h_xn, Wqkv_pk, bqkv, qf8, kbf, vf8);
    fused_attn_kernel<<<N_NODES / 4, 256, 0, stream>>>(qf8, kbf, vf8, srcs, rowptr, triplet_h,
                                                       ln_res_g, ln_res_b, x, h_xn);
    fused_ffn_kernel<<<M_PAD / 64, 512, 0, stream>>>(h_xn, Win_pk, Wout_pk, b_in, b_out, x, out);

    (void)in_sizes; (void)n_in; (void)out_size; (void)ws_size;
}

// Round 11
// 377.450 us; speedup vs baseline: 1.8752x; 1.4501x over previous
//
#include <hip/hip_runtime.h>
#include <math.h>

#define N_NODES 40000
#define M_PAD   40064      // 313 * 128
#define N_EDGES 640000
#define D       256
#define H       8
#define DFF     1024
#define D3      768
#define ATT_SCALE 0.0625f  // 256^-0.5
#define LN_EPS  1e-5f

typedef __attribute__((ext_vector_type(8))) short short8;
typedef __attribute__((ext_vector_type(4))) float f32x4;
typedef __attribute__((ext_vector_type(2))) float f32x2;

__device__ __forceinline__ unsigned short f2bf(float f) {
    unsigned int u = __builtin_bit_cast(unsigned int, f);
    u = (u + 0x7FFF + ((u >> 16) & 1)) >> 16;   // RTNE
    return (unsigned short)u;
}
__device__ __forceinline__ float bf2f(unsigned short u) {
    return __builtin_bit_cast(float, (unsigned int)u << 16);
}

// Fast exact-gelu: Abramowitz-Stegun 7.1.26 erf (|eps| <= 1.5e-7, branchless).
__device__ __forceinline__ float fast_gelu(float x) {
    const float z  = fabsf(x) * 0.70710678118654752f;
    const float t  = __builtin_amdgcn_rcpf(1.0f + 0.3275911f * z);
    float p = 1.061405429f;
    p = p * t - 1.453152027f;
    p = p * t + 1.421413741f;
    p = p * t - 0.284496736f;
    p = p * t + 0.254829592f;
    const float e  = __expf(-z * z);
    const float ea = 1.0f - p * t * e;          // erf(|x|/sqrt2)
    const float er = (x < 0.0f) ? -ea : ea;
    return 0.5f * x * (1.0f + er);
}

#define GLOAD_LDS16(g, l) \
    __builtin_amdgcn_global_load_lds((const __attribute__((address_space(1))) void*)(g), \
                                     (__attribute__((address_space(3))) void*)(l), 16, 0, 0)

// ---------------- fp8 e4m3 pack/unpack (HW cvt on gfx950, SW fallback) -----
#if __has_builtin(__builtin_amdgcn_cvt_pk_fp8_f32) && __has_builtin(__builtin_amdgcn_cvt_pk_f32_fp8)
#define HW_FP8 1
#else
#define HW_FP8 0
__device__ __forceinline__ unsigned char enc_e4m3(float f) {
    unsigned int u = __builtin_bit_cast(unsigned int, f);
    unsigned int s = (u >> 24) & 0x80;
    float a = fabsf(f);
    if (a >= 0x1p-6f) {
        unsigned int bits = __builtin_bit_cast(unsigned int, a);
        unsigned int q = bits >> 20;
        unsigned int rem = bits & 0xFFFFFu;
        q += (rem > 0x80000u) || ((rem == 0x80000u) && (q & 1));
        q -= 960;                          // rebias (120<<3)
        if (q > 126) q = 126;              // clamp to 448
        return (unsigned char)(s | q);
    }
    float t = a * 512.0f;
    unsigned int r = (unsigned int)rintf(t);   // RNE; 8 -> min normal naturally
    return (unsigned char)(s | r);
}
__device__ __forceinline__ float dec_e4m3(unsigned int v) {
    unsigned int em = v & 0x7f;
    float n = __builtin_bit_cast(float, (em << 20) + 0x3C000000u);
    float r = (em >= 8) ? n : (float)em * 0x1p-9f;
    return (v & 0x80) ? -r : r;
}
#endif

__device__ __forceinline__ unsigned int pack4_e4m3(float a, float b, float c, float d) {
#if HW_FP8
    unsigned int w = (unsigned int)__builtin_amdgcn_cvt_pk_fp8_f32(a, b, 0, false);
    w = (unsigned int)__builtin_amdgcn_cvt_pk_fp8_f32(c, d, (int)w, true);
    return w;
#else
    return (unsigned int)enc_e4m3(a) | ((unsigned int)enc_e4m3(b) << 8)
         | ((unsigned int)enc_e4m3(c) << 16) | ((unsigned int)enc_e4m3(d) << 24);
#endif
}
__device__ __forceinline__ void dec4_e4m3(unsigned int w, float& a, float& b, float& c, float& d) {
#if HW_FP8
    f32x2 lo = __builtin_amdgcn_cvt_pk_f32_fp8((int)w, false);
    f32x2 hi = __builtin_amdgcn_cvt_pk_f32_fp8((int)w, true);
    a = lo[0]; b = lo[1]; c = hi[0]; d = hi[1];
#else
    a = dec_e4m3(w & 0xff); b = dec_e4m3((w >> 8) & 0xff);
    c = dec_e4m3((w >> 16) & 0xff); d = dec_e4m3(w >> 24);
#endif
}

// ---------------------------------------------------------------------------
// Combined preprocessing (one launch): blocks [0, 10016) LayerNorm ->
// bf16 fragment order; [10016, 10368) weight pack x3; [10368, 12868)
// dst histogram. All independent; all precede their consumers.
// ---------------------------------------------------------------------------
#define NB_LN   (M_PAD / 4)          // 10016
#define NB_PACK 352
#define NB_HIST (N_EDGES / 256)      // 2500

__device__ __forceinline__ void ln_body(const float* __restrict__ in,
                                        const float* __restrict__ g,
                                        const float* __restrict__ b,
                                        unsigned short* __restrict__ out, int blk)
{
    const int row  = blk * 4 + (threadIdx.x >> 6);
    const int lane = threadIdx.x & 63;
    const size_t off = (((size_t)(row >> 4) * (D / 8) + (lane >> 1)) * 16 + (row & 15)) * 8
                       + (lane & 1) * 4;
    if (row >= N_NODES) {
        ushort4 z = {0, 0, 0, 0};
        *reinterpret_cast<ushort4*>(out + off) = z;
        return;
    }
    const float4 v = *reinterpret_cast<const float4*>(in + (size_t)row * D + lane * 4);
    float s  = v.x + v.y + v.z + v.w;
    float s2 = v.x * v.x + v.y * v.y + v.z * v.z + v.w * v.w;
#pragma unroll
    for (int o = 32; o > 0; o >>= 1) {
        s  += __shfl_xor(s,  o, 64);
        s2 += __shfl_xor(s2, o, 64);
    }
    const float mu  = s * (1.0f / D);
    const float var = s2 * (1.0f / D) - mu * mu;
    const float rs  = rsqrtf(var + LN_EPS);
    const float4 gg = *reinterpret_cast<const float4*>(g + lane * 4);
    const float4 bb = *reinterpret_cast<const float4*>(b + lane * 4);
    ushort4 o4;
    o4.x = f2bf((v.x - mu) * rs * gg.x + bb.x);
    o4.y = f2bf((v.y - mu) * rs * gg.y + bb.y);
    o4.z = f2bf((v.z - mu) * rs * gg.z + bb.z);
    o4.w = f2bf((v.w - mu) * rs * gg.w + bb.w);
    *reinterpret_cast<ushort4*>(out + off) = o4;
}

template <int K, int N>
__device__ __forceinline__ void pack_body(const float* __restrict__ W,
                                          unsigned short* __restrict__ Wpk, int blk)
{
    const int idx = blk * 256 + threadIdx.x;   // [N/16][K/8][16]
    const int ni  = idx & 15;
    const int kc  = (idx >> 4) % (K / 8);
    const int nt  = idx / (16 * (K / 8));
    const int n   = nt * 16 + ni;
    unsigned short o[8];
#pragma unroll
    for (int i = 0; i < 8; ++i)
        o[i] = f2bf(W[(size_t)(kc * 8 + i) * N + n]);
    *reinterpret_cast<short8*>(Wpk + (size_t)idx * 8) = *reinterpret_cast<short8*>(o);
}

__global__ __launch_bounds__(256) void prep_kernel(const float* __restrict__ triplet_h,
                                                   const float* __restrict__ ln_g,
                                                   const float* __restrict__ ln_b,
                                                   unsigned short* __restrict__ h_xn,
                                                   const float* __restrict__ Wqkv,
                                                   const float* __restrict__ W_in,
                                                   const float* __restrict__ W_out,
                                                   unsigned short* __restrict__ pq,
                                                   unsigned short* __restrict__ pi,
                                                   unsigned short* __restrict__ po,
                                                   const int* __restrict__ dst,
                                                   int* __restrict__ counts)
{
    const int b = blockIdx.x;
    if (b < NB_LN) {
        ln_body(triplet_h, ln_g, ln_b, h_xn, b);
    } else if (b < NB_LN + NB_PACK) {
        const int pb = b - NB_LN;
        if (pb < 96)       pack_body<D, D3 >(Wqkv, pq, pb);
        else if (pb < 224) pack_body<D, DFF>(W_in, pi, pb - 96);
        else               pack_body<DFF, D>(W_out, po, pb - 224);
    } else {
        const int i = (b - NB_LN - NB_PACK) * 256 + threadIdx.x;
        atomicAdd(&counts[dst[i]], 1);
    }
}

// ---------------------------------------------------------------------------
// bf16 MFMA GEMM -- m97 staging structure (128x128 tile, 4 waves, BK=32,
// global_load_lds width 16, barrier-synced K loop), LDS 16 KB, 4 blocks/CU.
// Panel-colocating XCD swizzle. MFMA operands SWAPPED: D maps to row
// r = lane&15, cols n = (lane>>4)*4+t -> 4 consecutive cols per thread.
// EPI 0: qkv 3-way split -> q fp8 (unscaled), k bf16 [node][256], v fp8
// EPI 1: bf16 C in fragment order [M/16][N/8][16][8] + fast exact gelu
// EPI 2: fp32 C row-major += Xadd, nontemporal f32x4 load/store
// ---------------------------------------------------------------------------
template <int EPI, int K, int N>
__global__ __launch_bounds__(256, 4) void mfma_gemm_kernel(const unsigned short* __restrict__ A,
                                                           const unsigned short* __restrict__ Bpk,
                                                           const float* __restrict__ bias,
                                                           void* __restrict__ Cout,
                                                           void* __restrict__ Cout2,
                                                           void* __restrict__ Cout3,
                                                           const float* __restrict__ Xadd)
{
    constexpr int C = N / 128;           // col tiles
    constexpr int P = M_PAD / 128;       // 313 row panels

    const int bid = blockIdx.x;
    const int xcd = bid & 7;
    const int t   = bid >> 3;
    const int c   = t % C;
    const int p   = (t / C) * 8 + xcd;
    if (p >= P) return;

    __shared__ unsigned short As[4096];   // [mt8][16][8] = 8 KB
    __shared__ unsigned short Bs[4096];

    const int tid  = threadIdx.x;
    const int wave = tid >> 6;
    const int lane = tid & 63;
    const int row0 = p * 128;
    const int col0 = c * 128;
    const int wm   = (wave >> 1) * 64;
    const int wn   = (wave & 1) * 64;
    const int g    = lane >> 4;
    const int q    = lane & 15;

    f32x4 acc[4][4] = {};

    const int fragoff = g * 128 + q * 8;

    for (int k0 = 0; k0 < K; k0 += 32) {
        const int kq = k0 >> 3;   // k-chunk index (K/8 units)
#pragma unroll
        for (int cc = 0; cc < 2; ++cc) {
            const int mt = wave * 2 + cc;                // 0..7
            const unsigned short* gA =
                A + ((size_t)(row0 / 16 + mt) * (K / 8) + kq) * 128 + lane * 8;
            GLOAD_LDS16(gA, &As[mt * 512]);
            const unsigned short* gB =
                Bpk + ((size_t)(col0 / 16 + mt) * (K / 8) + kq) * 128 + lane * 8;
            GLOAD_LDS16(gB, &Bs[mt * 512]);
        }
        __syncthreads();

        short8 af[4], bf[4];
#pragma unroll
        for (int i = 0; i < 4; ++i) {
            af[i] = *reinterpret_cast<const short8*>(&As[(wm / 16 + i) * 512 + fragoff]);
            bf[i] = *reinterpret_cast<const short8*>(&Bs[(wn / 16 + i) * 512 + fragoff]);
        }
#pragma unroll
        for (int i = 0; i < 4; ++i)
#pragma unroll
            for (int j = 0; j < 4; ++j)
                acc[i][j] = __builtin_amdgcn_mfma_f32_16x16x32_bf16(bf[j], af[i], acc[i][j], 0, 0, 0);
        __syncthreads();
    }

    // Swapped D layout: r = row0+wm+i*16+q ; n = col0+wn+j*16+g*4+t (t=0..3)
    if constexpr (EPI == 0) {
        if (col0 < 256) {        // q cols -> fp8, UNSCALED (scale folded into k)
            unsigned char* q8 = (unsigned char*)Cout;
#pragma unroll
            for (int j = 0; j < 4; ++j) {
                const int nb = col0 + wn + j * 16 + g * 4;
                const float4 bz = *reinterpret_cast<const float4*>(bias + nb);
#pragma unroll
                for (int i = 0; i < 4; ++i) {
                    const int r = row0 + wm + i * 16 + q;
                    if (r >= N_NODES) continue;
                    const unsigned int w = pack4_e4m3(acc[i][j][0] + bz.x, acc[i][j][1] + bz.y,
                                                      acc[i][j][2] + bz.z, acc[i][j][3] + bz.w);
                    *reinterpret_cast<unsigned int*>(q8 + (size_t)r * 256 + nb) = w;
                }
            }
        } else if (col0 < 512) { // k cols -> bf16 row-major [node][256]
            unsigned short* kb = (unsigned short*)Cout2;
#pragma unroll
            for (int j = 0; j < 4; ++j) {
                const int nb = col0 + wn + j * 16 + g * 4;
                const float4 bz = *reinterpret_cast<const float4*>(bias + nb);
#pragma unroll
                for (int i = 0; i < 4; ++i) {
                    const int r = row0 + wm + i * 16 + q;
                    if (r >= N_NODES) continue;
                    ushort4 u;
                    u.x = f2bf(acc[i][j][0] + bz.x);
                    u.y = f2bf(acc[i][j][1] + bz.y);
                    u.z = f2bf(acc[i][j][2] + bz.z);
                    u.w = f2bf(acc[i][j][3] + bz.w);
                    *reinterpret_cast<ushort4*>(kb + (size_t)r * 256 + (nb - 256)) = u;
                }
            }
        } else {                 // v cols -> fp8 [node][256]
            unsigned char* v8 = (unsigned char*)Cout3;
#pragma unroll
            for (int j = 0; j < 4; ++j) {
                const int nb = col0 + wn + j * 16 + g * 4;
                const float4 bz = *reinterpret_cast<const float4*>(bias + nb);
#pragma unroll
                for (int i = 0; i < 4; ++i) {
                    const int r = row0 + wm + i * 16 + q;
                    if (r >= N_NODES) continue;
                    const unsigned int w = pack4_e4m3(acc[i][j][0] + bz.x, acc[i][j][1] + bz.y,
                                                      acc[i][j][2] + bz.z, acc[i][j][3] + bz.w);
                    *reinterpret_cast<unsigned int*>(v8 + (size_t)r * 256 + (nb - 512)) = w;
                }
            }
        }
    } else if constexpr (EPI == 1) {
#pragma unroll
        for (int j = 0; j < 4; ++j) {
            const int nb = col0 + wn + j * 16 + g * 4;
            const float4 bz = *reinterpret_cast<const float4*>(bias + nb);
#pragma unroll
            for (int i = 0; i < 4; ++i) {
                const int r = row0 + wm + i * 16 + q;   // pad rows stored too (finite)
                const float o0 = fast_gelu(acc[i][j][0] + bz.x);
                const float o1 = fast_gelu(acc[i][j][1] + bz.y);
                const float o2 = fast_gelu(acc[i][j][2] + bz.z);
                const float o3 = fast_gelu(acc[i][j][3] + bz.w);
                const size_t off = (((size_t)(r >> 4) * (N / 8) + (nb >> 3)) * 16
                                    + (r & 15)) * 8 + (nb & 7);
                ushort4 u;
                u.x = f2bf(o0); u.y = f2bf(o1); u.z = f2bf(o2); u.w = f2bf(o3);
                *reinterpret_cast<ushort4*>((unsigned short*)Cout + off) = u;
            }
        }
    } else {
#pragma unroll
        for (int j = 0; j < 4; ++j) {
            const int nb = col0 + wn + j * 16 + g * 4;
            const float4 bz = *reinterpret_cast<const float4*>(bias + nb);
#pragma unroll
            for (int i = 0; i < 4; ++i) {
                const int r = row0 + wm + i * 16 + q;
                if (r >= N_NODES) continue;
                const f32x4 xd = __builtin_nontemporal_load(
                    reinterpret_cast<const f32x4*>(Xadd + (size_t)r * N + nb));
                f32x4 ov;
                ov[0] = acc[i][j][0] + bz.x + xd[0];
                ov[1] = acc[i][j][1] + bz.y + xd[1];
                ov[2] = acc[i][j][2] + bz.z + xd[2];
                ov[3] = acc[i][j][3] + bz.w + xd[3];
                __builtin_nontemporal_store(ov,
                    reinterpret_cast<f32x4*>((float*)Cout + (size_t)r * N + nb));
            }
        }
    }
}

// ---------------------------------------------------------------------------
// CSR build (scan + fill; hist lives in prep_kernel)
// ---------------------------------------------------------------------------
// Two-pass, ARRAY-FREE scan (int c[40] spilled to scratch -> was 64 us).
__global__ __launch_bounds__(1024) void scan_kernel(const int* __restrict__ counts,
                                                    int* __restrict__ rowptr,
                                                    int* __restrict__ cursor)
{
    const int PER = 40;
    const int tid  = threadIdx.x;
    const int base = tid * PER;
    const bool act = (base < N_NODES);     // threads 0..999 own 40 each
    int s = 0;
    if (act) {
#pragma unroll
        for (int i = 0; i < PER / 4; ++i) {
            const int4 c4 = *reinterpret_cast<const int4*>(counts + base + i * 4);
            s += (c4.x + c4.y) + (c4.z + c4.w);
        }
    }
    __shared__ int sm[1024];
    sm[tid] = s;
    __syncthreads();
    for (int off = 1; off < 1024; off <<= 1) {
        int t = (tid >= off) ? sm[tid - off] : 0;
        __syncthreads();
        sm[tid] += t;
        __syncthreads();
    }
    int run = sm[tid] - s;                 // exclusive prefix of this chunk
    if (act) {
#pragma unroll
        for (int i = 0; i < PER / 4; ++i) {
            const int4 c4 = *reinterpret_cast<const int4*>(counts + base + i * 4);
            int4 r4;
            r4.x = run;
            r4.y = r4.x + c4.x;
            r4.z = r4.y + c4.y;
            r4.w = r4.z + c4.z;
            run  = r4.w + c4.w;
            *reinterpret_cast<int4*>(rowptr + base + i * 4) = r4;
            *reinterpret_cast<int4*>(cursor + base + i * 4) = r4;
        }
    }
    if (tid == 1023) rowptr[N_NODES] = sm[1023];
}

__global__ __launch_bounds__(256) void fill_kernel(const int* __restrict__ src,
                                                   const int* __restrict__ dst,
                                                   int* __restrict__ cursor,
                                                   int* __restrict__ srcs)
{
    const int e = blockIdx.x * 256 + threadIdx.x;
    const int pos = atomicAdd(&cursor[dst[e]], 1);
    if (pos >= 0 && pos < N_EDGES) srcs[pos] = src[e];
}

// ---------------------------------------------------------------------------
// Fused attention: q fp8 (256 B/row, gathered) + v fp8 (256 B/row, gathered)
// + k bf16 (512 B/row, loaded once per dst node). Edge gather = 512 B.
// One wave per dst node; src list coalesce-prefetched, readlane broadcast,
// 4-edge unroll. k scaled by ATT_SCALE at load.
// Outputs: x fp32 row-major, xn bf16 in fragment order.
// ---------------------------------------------------------------------------
__global__ __launch_bounds__(256) void fused_attn_kernel(const unsigned char* __restrict__ qf8,
                                                         const unsigned short* __restrict__ kbf,
                                                         const unsigned char* __restrict__ vf8,
                                                         const int* __restrict__ srcs,
                                                         const int* __restrict__ rowptr,
                                                         const float* __restrict__ triplet_h,
                                                         const float* __restrict__ g,
                                                         const float* __restrict__ b,
                                                         float* __restrict__ x,
                                                         unsigned short* __restrict__ xn)
{
    const int node = blockIdx.x * 4 + (threadIdx.x >> 6);
    const int lane = threadIdx.x & 63;
    int beg = rowptr[node];
    int end = rowptr[node + 1];
    beg = max(0, min(beg, N_EDGES));
    end = max(beg, min(end, N_EDGES));
    const int deg = end - beg;

    const ushort4 ku = *reinterpret_cast<const ushort4*>(
        kbf + (size_t)node * 256 + lane * 4);
    const float k0 = bf2f(ku.x) * ATT_SCALE, k1 = bf2f(ku.y) * ATT_SCALE;
    const float k2 = bf2f(ku.z) * ATT_SCALE, k3 = bf2f(ku.w) * ATT_SCALE;

    float dsum = 0.0f;
    float4 acc = {0.0f, 0.0f, 0.0f, 0.0f};

    for (int base = 0; base < deg; base += 64) {
        const int cnt = min(64, deg - base);
        const int idx = base + lane;
        const int sv = (idx < deg) ? srcs[beg + idx] : 0;   // coalesced prefetch
        int j = 0;
        for (; j + 4 <= cnt; j += 4) {
            const int s0 = __builtin_amdgcn_readlane(sv, j);
            const int s1 = __builtin_amdgcn_readlane(sv, j + 1);
            const int s2 = __builtin_amdgcn_readlane(sv, j + 2);
            const int s3 = __builtin_amdgcn_readlane(sv, j + 3);
            const unsigned int qa = *reinterpret_cast<const unsigned int*>(qf8 + (size_t)s0 * 256 + lane * 4);
            const unsigned int qb = *reinterpret_cast<const unsigned int*>(qf8 + (size_t)s1 * 256 + lane * 4);
            const unsigned int qc = *reinterpret_cast<const unsigned int*>(qf8 + (size_t)s2 * 256 + lane * 4);
            const unsigned int qd = *reinterpret_cast<const unsigned int*>(qf8 + (size_t)s3 * 256 + lane * 4);
            const unsigned int va = *reinterpret_cast<const unsigned int*>(vf8 + (size_t)s0 * 256 + lane * 4);
            const unsigned int vb = *reinterpret_cast<const unsigned int*>(vf8 + (size_t)s1 * 256 + lane * 4);
            const unsigned int vc = *reinterpret_cast<const unsigned int*>(vf8 + (size_t)s2 * 256 + lane * 4);
            const unsigned int vd = *reinterpret_cast<const unsigned int*>(vf8 + (size_t)s3 * 256 + lane * 4);
            float a0, a1, a2, a3;
            dec4_e4m3(qa, a0, a1, a2, a3);
            float p0 = a0 * k0 + a1 * k1 + a2 * k2 + a3 * k3;
            dec4_e4m3(qb, a0, a1, a2, a3);
            float p1 = a0 * k0 + a1 * k1 + a2 * k2 + a3 * k3;
            dec4_e4m3(qc, a0, a1, a2, a3);
            float p2 = a0 * k0 + a1 * k1 + a2 * k2 + a3 * k3;
            dec4_e4m3(qd, a0, a1, a2, a3);
            float p3 = a0 * k0 + a1 * k1 + a2 * k2 + a3 * k3;
            p0 += __shfl_xor(p0, 1, 64); p1 += __shfl_xor(p1, 1, 64);
            p2 += __shfl_xor(p2, 1, 64); p3 += __shfl_xor(p3, 1, 64);
            p0 += __shfl_xor(p0, 2, 64); p1 += __shfl_xor(p1, 2, 64);
            p2 += __shfl_xor(p2, 2, 64); p3 += __shfl_xor(p3, 2, 64);
            p0 += __shfl_xor(p0, 4, 64); p1 += __shfl_xor(p1, 4, 64);
            p2 += __shfl_xor(p2, 4, 64); p3 += __shfl_xor(p3, 4, 64);
            const float w0 = __expf(p0), w1 = __expf(p1), w2 = __expf(p2), w3 = __expf(p3);
            float v0, v1, v2, v3;
            dec4_e4m3(va, v0, v1, v2, v3);
            acc.x += w0 * v0; acc.y += w0 * v1; acc.z += w0 * v2; acc.w += w0 * v3;
            dec4_e4m3(vb, v0, v1, v2, v3);
            acc.x += w1 * v0; acc.y += w1 * v1; acc.z += w1 * v2; acc.w += w1 * v3;
            dec4_e4m3(vc, v0, v1, v2, v3);
            acc.x += w2 * v0; acc.y += w2 * v1; acc.z += w2 * v2; acc.w += w2 * v3;
            dec4_e4m3(vd, v0, v1, v2, v3);
            acc.x += w3 * v0; acc.y += w3 * v1; acc.z += w3 * v2; acc.w += w3 * v3;
            dsum += (w0 + w1) + (w2 + w3);
        }
        for (; j < cnt; ++j) {
            const int s0 = __builtin_amdgcn_readlane(sv, j);
            const unsigned int qa = *reinterpret_cast<const unsigned int*>(qf8 + (size_t)s0 * 256 + lane * 4);
            const unsigned int va = *reinterpret_cast<const unsigned int*>(vf8 + (size_t)s0 * 256 + lane * 4);
            float a0, a1, a2, a3;
            dec4_e4m3(qa, a0, a1, a2, a3);
            float p0 = a0 * k0 + a1 * k1 + a2 * k2 + a3 * k3;
            p0 += __shfl_xor(p0, 1, 64);
            p0 += __shfl_xor(p0, 2, 64);
            p0 += __shfl_xor(p0, 4, 64);
            const float w0 = __expf(p0);
            float v0, v1, v2, v3;
            dec4_e4m3(va, v0, v1, v2, v3);
            acc.x += w0 * v0; acc.y += w0 * v1; acc.z += w0 * v2; acc.w += w0 * v3;
            dsum += w0;
        }
    }
    const float inv = (deg > 0) ? 1.0f / dsum : 0.0f;

    const float4 th = *reinterpret_cast<const float4*>(
        triplet_h + (size_t)node * D + lane * 4);
    float4 xv;
    xv.x = th.x + acc.x * inv;
    xv.y = th.y + acc.y * inv;
    xv.z = th.z + acc.z * inv;
    xv.w = th.w + acc.w * inv;
    *reinterpret_cast<float4*>(x + (size_t)node * D + lane * 4) = xv;

    // LN2 across the wave
    float s  = xv.x + xv.y + xv.z + xv.w;
    float s2 = xv.x * xv.x + xv.y * xv.y + xv.z * xv.z + xv.w * xv.w;
#pragma unroll
    for (int o = 32; o > 0; o >>= 1) {
        s  += __shfl_xor(s,  o, 64);
        s2 += __shfl_xor(s2, o, 64);
    }
    const float mu  = s * (1.0f / D);
    const float var = s2 * (1.0f / D) - mu * mu;
    const float rs  = rsqrtf(var + LN_EPS);
    const float4 gg = *reinterpret_cast<const float4*>(g + lane * 4);
    const float4 bb = *reinterpret_cast<const float4*>(b + lane * 4);
    ushort4 o4;
    o4.x = f2bf((xv.x - mu) * rs * gg.x + bb.x);
    o4.y = f2bf((xv.y - mu) * rs * gg.y + bb.y);
    o4.z = f2bf((xv.z - mu) * rs * gg.z + bb.z);
    o4.w = f2bf((xv.w - mu) * rs * gg.w + bb.w);
    const size_t off = (((size_t)(node >> 4) * (D / 8) + (lane >> 1)) * 16 + (node & 15)) * 8
                       + (lane & 1) * 4;
    *reinterpret_cast<ushort4*>(xn + off) = o4;
}

// ---------------------------------------------------------------------------
extern "C" void kernel_launch(void* const* d_in, const int* in_sizes, int n_in,
                              void* d_out, int out_size, void* d_ws, size_t ws_size,
                              hipStream_t stream)
{
    const float* triplet_h = (const float*)d_in[0];
    const int*   src       = (const int*)d_in[1];
    const int*   dst       = (const int*)d_in[2];
    const float* Wqkv      = (const float*)d_in[3];
    const float* bqkv      = (const float*)d_in[4];
    const float* ln_attn_g = (const float*)d_in[5];
    const float* ln_attn_b = (const float*)d_in[6];
    const float* ln_res_g  = (const float*)d_in[7];
    const float* ln_res_b  = (const float*)d_in[8];
    const float* W_in      = (const float*)d_in[9];
    const float* b_in      = (const float*)d_in[10];
    const float* W_out     = (const float*)d_in[11];
    const float* b_out     = (const float*)d_in[12];
    float* out = (float*)d_out;

    // Workspace (~175 MB, under ceiling):
    char* w = (char*)d_ws;
    unsigned short* bufA = (unsigned short*)w;   // kbf (attn) then a1 (FFN)
    w += (size_t)M_PAD * DFF * sizeof(unsigned short);
    unsigned short* h_xn = (unsigned short*)w;  w += (size_t)M_PAD * D * sizeof(unsigned short);
    float*          x    = (float*)w;           w += (size_t)N_NODES * D * sizeof(float);
    unsigned char*  qf8  = (unsigned char*)w;   w += (size_t)N_NODES * 256;
    unsigned char*  vf8  = (unsigned char*)w;   w += (size_t)N_NODES * 256;
    unsigned short* Wqkv_pk = (unsigned short*)w; w += (size_t)D * D3 * sizeof(unsigned short);
    unsigned short* Win_pk  = (unsigned short*)w; w += (size_t)D * DFF * sizeof(unsigned short);
    unsigned short* Wout_pk = (unsigned short*)w; w += (size_t)DFF * D * sizeof(unsigned short);
    int* counts = (int*)w;  w += (size_t)N_NODES * sizeof(int);
    int* rowptr = (int*)w;  w += (size_t)(N_NODES + 1) * sizeof(int);
    int* cursor = (int*)w;  w += (size_t)N_NODES * sizeof(int);
    int* srcs   = (int*)w;  w += (size_t)N_EDGES * sizeof(int);

    unsigned short* kbf = bufA;  // [40000][256] bf16 (k), dead after fused_attn
    unsigned short* a1  = bufA;  // [M_PAD/16][128][16][8] bf16 frag, live FFN only

    // ---- preprocessing (one launch: LN + weight packs + dst histogram) ----
    (void)hipMemsetAsync(counts, 0, (size_t)N_NODES * sizeof(int), stream);
    prep_kernel<<<NB_LN + NB_PACK + NB_HIST, 256, 0, stream>>>(
        triplet_h, ln_attn_g, ln_attn_b, h_xn,
        Wqkv, W_in, W_out, Wqkv_pk, Win_pk, Wout_pk, dst, counts);
    scan_kernel<<<1, 1024, 0, stream>>>(counts, rowptr, cursor);
    fill_kernel<<<N_EDGES / 256, 256, 0, stream>>>(src, dst, cursor, srcs);

    // ---- main pipeline ----
    mfma_gemm_kernel<0, D, D3><<<((M_PAD / 128 + 7) / 8) * 8 * (D3 / 128), 256, 0, stream>>>(
        h_xn, Wqkv_pk, bqkv, qf8, kbf, vf8, nullptr);
    fused_attn_kernel<<<N_NODES / 4, 256, 0, stream>>>(qf8, kbf, vf8, srcs, rowptr, triplet_h,
                                                       ln_res_g, ln_res_b, x, h_xn);
    // kbf dead; a1 overwrites it (EPI1 stores pad rows too -> no memset needed)
    mfma_gemm_kernel<1, D, DFF><<<((M_PAD / 128 + 7) / 8) * 8 * (DFF / 128), 256, 0, stream>>>(
        h_xn, Win_pk, b_in, a1, nullptr, nullptr, nullptr);
    mfma_gemm_kernel<2, DFF, D><<<((M_PAD / 128 + 7) / 8) * 8 * (D / 128), 256, 0, stream>>>(
        a1, Wout_pk, b_out, out, nullptr, nullptr, x);

    (void)in_sizes; (void)n_in; (void)out_size; (void)ws_size;
}

// Round 12
// 346.645 us; speedup vs baseline: 2.0418x; 1.0889x over previous
//
#include <hip/hip_runtime.h>
#include <math.h>

#define N_NODES 40000
#define M_PAD   40064      // 313 * 128
#define N_EDGES 640000
#define D       256
#define H       8
#define DFF     1024
#define D3      768
#define ATT_SCALE 0.0625f  // 256^-0.5
#define LN_EPS  1e-5f

typedef __attribute__((ext_vector_type(8))) short short8;
typedef __attribute__((ext_vector_type(4))) float f32x4;
typedef __attribute__((ext_vector_type(2))) float f32x2;

__device__ __forceinline__ unsigned short f2bf(float f) {
    unsigned int u = __builtin_bit_cast(unsigned int, f);
    u = (u + 0x7FFF + ((u >> 16) & 1)) >> 16;   // RTNE
    return (unsigned short)u;
}
__device__ __forceinline__ float bf2f(unsigned short u) {
    return __builtin_bit_cast(float, (unsigned int)u << 16);
}

// Fast exact-gelu: Abramowitz-Stegun 7.1.26 erf (|eps| <= 1.5e-7, branchless).
__device__ __forceinline__ float fast_gelu(float x) {
    const float z  = fabsf(x) * 0.70710678118654752f;
    const float t  = __builtin_amdgcn_rcpf(1.0f + 0.3275911f * z);
    float p = 1.061405429f;
    p = p * t - 1.453152027f;
    p = p * t + 1.421413741f;
    p = p * t - 0.284496736f;
    p = p * t + 0.254829592f;
    const float e  = __expf(-z * z);
    const float ea = 1.0f - p * t * e;          // erf(|x|/sqrt2)
    const float er = (x < 0.0f) ? -ea : ea;
    return 0.5f * x * (1.0f + er);
}

#define GLOAD_LDS16(g, l) \
    __builtin_amdgcn_global_load_lds((const __attribute__((address_space(1))) void*)(g), \
                                     (__attribute__((address_space(3))) void*)(l), 16, 0, 0)

// ---------------- fp8 e4m3 pack/unpack (HW cvt on gfx950, SW fallback) -----
#if __has_builtin(__builtin_amdgcn_cvt_pk_fp8_f32) && __has_builtin(__builtin_amdgcn_cvt_pk_f32_fp8)
#define HW_FP8 1
#else
#define HW_FP8 0
__device__ __forceinline__ unsigned char enc_e4m3(float f) {
    unsigned int u = __builtin_bit_cast(unsigned int, f);
    unsigned int s = (u >> 24) & 0x80;
    float a = fabsf(f);
    if (a >= 0x1p-6f) {
        unsigned int bits = __builtin_bit_cast(unsigned int, a);
        unsigned int q = bits >> 20;
        unsigned int rem = bits & 0xFFFFFu;
        q += (rem > 0x80000u) || ((rem == 0x80000u) && (q & 1));
        q -= 960;                          // rebias (120<<3)
        if (q > 126) q = 126;              // clamp to 448
        return (unsigned char)(s | q);
    }
    float t = a * 512.0f;
    unsigned int r = (unsigned int)rintf(t);   // RNE; 8 -> min normal naturally
    return (unsigned char)(s | r);
}
__device__ __forceinline__ float dec_e4m3(unsigned int v) {
    unsigned int em = v & 0x7f;
    float n = __builtin_bit_cast(float, (em << 20) + 0x3C000000u);
    float r = (em >= 8) ? n : (float)em * 0x1p-9f;
    return (v & 0x80) ? -r : r;
}
#endif

__device__ __forceinline__ unsigned int pack4_e4m3(float a, float b, float c, float d) {
#if HW_FP8
    unsigned int w = (unsigned int)__builtin_amdgcn_cvt_pk_fp8_f32(a, b, 0, false);
    w = (unsigned int)__builtin_amdgcn_cvt_pk_fp8_f32(c, d, (int)w, true);
    return w;
#else
    return (unsigned int)enc_e4m3(a) | ((unsigned int)enc_e4m3(b) << 8)
         | ((unsigned int)enc_e4m3(c) << 16) | ((unsigned int)enc_e4m3(d) << 24);
#endif
}
__device__ __forceinline__ void dec4_e4m3(unsigned int w, float& a, float& b, float& c, float& d) {
#if HW_FP8
    f32x2 lo = __builtin_amdgcn_cvt_pk_f32_fp8((int)w, false);
    f32x2 hi = __builtin_amdgcn_cvt_pk_f32_fp8((int)w, true);
    a = lo[0]; b = lo[1]; c = hi[0]; d = hi[1];
#else
    a = dec_e4m3(w & 0xff); b = dec_e4m3((w >> 8) & 0xff);
    c = dec_e4m3((w >> 16) & 0xff); d = dec_e4m3(w >> 24);
#endif
}

// ---------------------------------------------------------------------------
// Combined preprocessing (one launch): blocks [0, 10016) LayerNorm ->
// bf16 fragment order; [10016, 10368) weight pack x3; [10368, 12868)
// dst histogram WITH rank capture (atomic's old value = within-bucket rank,
// making the later fill atomic-free).
// ---------------------------------------------------------------------------
#define NB_LN   (M_PAD / 4)          // 10016
#define NB_PACK 352
#define NB_HIST (N_EDGES / 256)      // 2500

__device__ __forceinline__ void ln_body(const float* __restrict__ in,
                                        const float* __restrict__ g,
                                        const float* __restrict__ b,
                                        unsigned short* __restrict__ out, int blk)
{
    const int row  = blk * 4 + (threadIdx.x >> 6);
    const int lane = threadIdx.x & 63;
    const size_t off = (((size_t)(row >> 4) * (D / 8) + (lane >> 1)) * 16 + (row & 15)) * 8
                       + (lane & 1) * 4;
    if (row >= N_NODES) {
        ushort4 z = {0, 0, 0, 0};
        *reinterpret_cast<ushort4*>(out + off) = z;
        return;
    }
    const float4 v = *reinterpret_cast<const float4*>(in + (size_t)row * D + lane * 4);
    float s  = v.x + v.y + v.z + v.w;
    float s2 = v.x * v.x + v.y * v.y + v.z * v.z + v.w * v.w;
#pragma unroll
    for (int o = 32; o > 0; o >>= 1) {
        s  += __shfl_xor(s,  o, 64);
        s2 += __shfl_xor(s2, o, 64);
    }
    const float mu  = s * (1.0f / D);
    const float var = s2 * (1.0f / D) - mu * mu;
    const float rs  = rsqrtf(var + LN_EPS);
    const float4 gg = *reinterpret_cast<const float4*>(g + lane * 4);
    const float4 bb = *reinterpret_cast<const float4*>(b + lane * 4);
    ushort4 o4;
    o4.x = f2bf((v.x - mu) * rs * gg.x + bb.x);
    o4.y = f2bf((v.y - mu) * rs * gg.y + bb.y);
    o4.z = f2bf((v.z - mu) * rs * gg.z + bb.z);
    o4.w = f2bf((v.w - mu) * rs * gg.w + bb.w);
    *reinterpret_cast<ushort4*>(out + off) = o4;
}

template <int K, int N>
__device__ __forceinline__ void pack_body(const float* __restrict__ W,
                                          unsigned short* __restrict__ Wpk, int blk)
{
    const int idx = blk * 256 + threadIdx.x;   // [N/16][K/8][16]
    const int ni  = idx & 15;
    const int kc  = (idx >> 4) % (K / 8);
    const int nt  = idx / (16 * (K / 8));
    const int n   = nt * 16 + ni;
    unsigned short o[8];
#pragma unroll
    for (int i = 0; i < 8; ++i)
        o[i] = f2bf(W[(size_t)(kc * 8 + i) * N + n]);
    *reinterpret_cast<short8*>(Wpk + (size_t)idx * 8) = *reinterpret_cast<short8*>(o);
}

__global__ __launch_bounds__(256) void prep_kernel(const float* __restrict__ triplet_h,
                                                   const float* __restrict__ ln_g,
                                                   const float* __restrict__ ln_b,
                                                   unsigned short* __restrict__ h_xn,
                                                   const float* __restrict__ Wqkv,
                                                   const float* __restrict__ W_in,
                                                   const float* __restrict__ W_out,
                                                   unsigned short* __restrict__ pq,
                                                   unsigned short* __restrict__ pi,
                                                   unsigned short* __restrict__ po,
                                                   const int* __restrict__ dst,
                                                   int* __restrict__ counts,
                                                   int* __restrict__ rank)
{
    const int b = blockIdx.x;
    if (b < NB_LN) {
        ln_body(triplet_h, ln_g, ln_b, h_xn, b);
    } else if (b < NB_LN + NB_PACK) {
        const int pb = b - NB_LN;
        if (pb < 96)       pack_body<D, D3 >(Wqkv, pq, pb);
        else if (pb < 224) pack_body<D, DFF>(W_in, pi, pb - 96);
        else               pack_body<DFF, D>(W_out, po, pb - 224);
    } else {
        const int i = (b - NB_LN - NB_PACK) * 256 + threadIdx.x;
        rank[i] = atomicAdd(&counts[dst[i]], 1);
    }
}

// ---------------------------------------------------------------------------
// bf16 MFMA GEMM -- m97 staging structure (128x128 tile, 4 waves, BK=32,
// global_load_lds width 16, barrier-synced K loop), LDS 16 KB, 4 blocks/CU.
// Panel-colocating XCD swizzle. MFMA operands SWAPPED: D maps to row
// r = lane&15, cols n = (lane>>4)*4+t -> 4 consecutive cols per thread.
// EPI 0: qkv 3-way split (q fp8 / k bf16 / v fp8) + ONE EXTRA TAIL BLOCK
//        running the 256-thread CSR scan (hides its ~8 us under the GEMM).
// EPI 1: bf16 C in fragment order [M/16][N/8][16][8] + fast exact gelu
// EPI 2: fp32 C row-major += Xadd, nontemporal f32x4 load/store
// ---------------------------------------------------------------------------
template <int EPI, int K, int N>
__global__ __launch_bounds__(256, 4) void mfma_gemm_kernel(const unsigned short* __restrict__ A,
                                                           const unsigned short* __restrict__ Bpk,
                                                           const float* __restrict__ bias,
                                                           void* __restrict__ Cout,
                                                           void* __restrict__ Cout2,
                                                           void* __restrict__ Cout3,
                                                           const float* __restrict__ Xadd,
                                                           const int* __restrict__ sc_counts,
                                                           int* __restrict__ sc_rowptr)
{
    constexpr int C     = N / 128;           // col tiles
    constexpr int P     = M_PAD / 128;       // 313 row panels
    constexpr int NBLK0 = ((P + 7) / 8) * 8 * C;   // GEMM blocks before scan tail

    const int bid = blockIdx.x;

    if constexpr (EPI == 0) {
        if (bid == NBLK0) {
            // ---- CSR scan tail block: 256 thr x 160 nodes (250 active) ----
            const int PER = 160;
            const int tid  = threadIdx.x;
            const int base = tid * PER;
            const bool act = (base < N_NODES);      // tids 0..249
            int s = 0;
            if (act) {
#pragma unroll
                for (int i = 0; i < PER / 4; ++i) {
                    const int4 c4 = *reinterpret_cast<const int4*>(sc_counts + base + i * 4);
                    s += (c4.x + c4.y) + (c4.z + c4.w);
                }
            }
            __shared__ int sm2[256];
            sm2[tid] = s;
            __syncthreads();
            for (int off = 1; off < 256; off <<= 1) {
                int t = (tid >= off) ? sm2[tid - off] : 0;
                __syncthreads();
                sm2[tid] += t;
                __syncthreads();
            }
            int run = sm2[tid] - s;                 // exclusive prefix
            if (act) {
#pragma unroll
                for (int i = 0; i < PER / 4; ++i) {
                    const int4 c4 = *reinterpret_cast<const int4*>(sc_counts + base + i * 4);
                    int4 r4;
                    r4.x = run;
                    r4.y = r4.x + c4.x;
                    r4.z = r4.y + c4.y;
                    r4.w = r4.z + c4.z;
                    run  = r4.w + c4.w;
                    *reinterpret_cast<int4*>(sc_rowptr + base + i * 4) = r4;
                }
            }
            if (tid == 255) sc_rowptr[N_NODES] = sm2[255];
            return;
        }
    }

    const int xcd = bid & 7;
    const int t   = bid >> 3;
    const int c   = t % C;
    const int p   = (t / C) * 8 + xcd;
    if (p >= P) return;

    __shared__ unsigned short As[4096];   // [mt8][16][8] = 8 KB
    __shared__ unsigned short Bs[4096];

    const int tid  = threadIdx.x;
    const int wave = tid >> 6;
    const int lane = tid & 63;
    const int row0 = p * 128;
    const int col0 = c * 128;
    const int wm   = (wave >> 1) * 64;
    const int wn   = (wave & 1) * 64;
    const int g    = lane >> 4;
    const int q    = lane & 15;

    f32x4 acc[4][4] = {};

    const int fragoff = g * 128 + q * 8;

    for (int k0 = 0; k0 < K; k0 += 32) {
        const int kq = k0 >> 3;   // k-chunk index (K/8 units)
#pragma unroll
        for (int cc = 0; cc < 2; ++cc) {
            const int mt = wave * 2 + cc;                // 0..7
            const unsigned short* gA =
                A + ((size_t)(row0 / 16 + mt) * (K / 8) + kq) * 128 + lane * 8;
            GLOAD_LDS16(gA, &As[mt * 512]);
            const unsigned short* gB =
                Bpk + ((size_t)(col0 / 16 + mt) * (K / 8) + kq) * 128 + lane * 8;
            GLOAD_LDS16(gB, &Bs[mt * 512]);
        }
        __syncthreads();

        short8 af[4], bf[4];
#pragma unroll
        for (int i = 0; i < 4; ++i) {
            af[i] = *reinterpret_cast<const short8*>(&As[(wm / 16 + i) * 512 + fragoff]);
            bf[i] = *reinterpret_cast<const short8*>(&Bs[(wn / 16 + i) * 512 + fragoff]);
        }
#pragma unroll
        for (int i = 0; i < 4; ++i)
#pragma unroll
            for (int j = 0; j < 4; ++j)
                acc[i][j] = __builtin_amdgcn_mfma_f32_16x16x32_bf16(bf[j], af[i], acc[i][j], 0, 0, 0);
        __syncthreads();
    }

    // Swapped D layout: r = row0+wm+i*16+q ; n = col0+wn+j*16+g*4+t (t=0..3)
    if constexpr (EPI == 0) {
        if (col0 < 256) {        // q cols -> fp8, UNSCALED (scale folded into k)
            unsigned char* q8 = (unsigned char*)Cout;
#pragma unroll
            for (int j = 0; j < 4; ++j) {
                const int nb = col0 + wn + j * 16 + g * 4;
                const float4 bz = *reinterpret_cast<const float4*>(bias + nb);
#pragma unroll
                for (int i = 0; i < 4; ++i) {
                    const int r = row0 + wm + i * 16 + q;
                    if (r >= N_NODES) continue;
                    const unsigned int w = pack4_e4m3(acc[i][j][0] + bz.x, acc[i][j][1] + bz.y,
                                                      acc[i][j][2] + bz.z, acc[i][j][3] + bz.w);
                    *reinterpret_cast<unsigned int*>(q8 + (size_t)r * 256 + nb) = w;
                }
            }
        } else if (col0 < 512) { // k cols -> bf16 row-major [node][256]
            unsigned short* kb = (unsigned short*)Cout2;
#pragma unroll
            for (int j = 0; j < 4; ++j) {
                const int nb = col0 + wn + j * 16 + g * 4;
                const float4 bz = *reinterpret_cast<const float4*>(bias + nb);
#pragma unroll
                for (int i = 0; i < 4; ++i) {
                    const int r = row0 + wm + i * 16 + q;
                    if (r >= N_NODES) continue;
                    ushort4 u;
                    u.x = f2bf(acc[i][j][0] + bz.x);
                    u.y = f2bf(acc[i][j][1] + bz.y);
                    u.z = f2bf(acc[i][j][2] + bz.z);
                    u.w = f2bf(acc[i][j][3] + bz.w);
                    *reinterpret_cast<ushort4*>(kb + (size_t)r * 256 + (nb - 256)) = u;
                }
            }
        } else {                 // v cols -> fp8 [node][256]
            unsigned char* v8 = (unsigned char*)Cout3;
#pragma unroll
            for (int j = 0; j < 4; ++j) {
                const int nb = col0 + wn + j * 16 + g * 4;
                const float4 bz = *reinterpret_cast<const float4*>(bias + nb);
#pragma unroll
                for (int i = 0; i < 4; ++i) {
                    const int r = row0 + wm + i * 16 + q;
                    if (r >= N_NODES) continue;
                    const unsigned int w = pack4_e4m3(acc[i][j][0] + bz.x, acc[i][j][1] + bz.y,
                                                      acc[i][j][2] + bz.z, acc[i][j][3] + bz.w);
                    *reinterpret_cast<unsigned int*>(v8 + (size_t)r * 256 + (nb - 512)) = w;
                }
            }
        }
    } else if constexpr (EPI == 1) {
#pragma unroll
        for (int j = 0; j < 4; ++j) {
            const int nb = col0 + wn + j * 16 + g * 4;
            const float4 bz = *reinterpret_cast<const float4*>(bias + nb);
#pragma unroll
            for (int i = 0; i < 4; ++i) {
                const int r = row0 + wm + i * 16 + q;   // pad rows stored too (finite)
                const float o0 = fast_gelu(acc[i][j][0] + bz.x);
                const float o1 = fast_gelu(acc[i][j][1] + bz.y);
                const float o2 = fast_gelu(acc[i][j][2] + bz.z);
                const float o3 = fast_gelu(acc[i][j][3] + bz.w);
                const size_t off = (((size_t)(r >> 4) * (N / 8) + (nb >> 3)) * 16
                                    + (r & 15)) * 8 + (nb & 7);
                ushort4 u;
                u.x = f2bf(o0); u.y = f2bf(o1); u.z = f2bf(o2); u.w = f2bf(o3);
                *reinterpret_cast<ushort4*>((unsigned short*)Cout + off) = u;
            }
        }
    } else {
#pragma unroll
        for (int j = 0; j < 4; ++j) {
            const int nb = col0 + wn + j * 16 + g * 4;
            const float4 bz = *reinterpret_cast<const float4*>(bias + nb);
#pragma unroll
            for (int i = 0; i < 4; ++i) {
                const int r = row0 + wm + i * 16 + q;
                if (r >= N_NODES) continue;
                const f32x4 xd = __builtin_nontemporal_load(
                    reinterpret_cast<const f32x4*>(Xadd + (size_t)r * N + nb));
                f32x4 ov;
                ov[0] = acc[i][j][0] + bz.x + xd[0];
                ov[1] = acc[i][j][1] + bz.y + xd[1];
                ov[2] = acc[i][j][2] + bz.z + xd[2];
                ov[3] = acc[i][j][3] + bz.w + xd[3];
                __builtin_nontemporal_store(ov,
                    reinterpret_cast<f32x4*>((float*)Cout + (size_t)r * N + nb));
            }
        }
    }
}

// ---------------------------------------------------------------------------
// Atomic-free CSR fill: pos = rowptr[dst] + rank (rank captured in prep's
// histogram atomic). 3 coalesced reads + 1 random 4 B write, no RMW chain.
// ---------------------------------------------------------------------------
__global__ __launch_bounds__(256) void fill_kernel(const int* __restrict__ src,
                                                   const int* __restrict__ dst,
                                                   const int* __restrict__ rowptr,
                                                   const int* __restrict__ rank,
                                                   int* __restrict__ srcs)
{
    const int e = blockIdx.x * 256 + threadIdx.x;
    const int pos = rowptr[dst[e]] + rank[e];
    if ((unsigned)pos < N_EDGES) srcs[pos] = src[e];
}

// ---------------------------------------------------------------------------
// Fused attention: q fp8 (256 B/row, gathered) + v fp8 (256 B/row, gathered)
// + k bf16 (512 B/row, loaded once per dst node). Edge gather = 512 B.
// One wave per dst node; src list coalesce-prefetched, readlane broadcast,
// 4-edge unroll. k scaled by ATT_SCALE at load.
// Outputs: x fp32 row-major, xn bf16 in fragment order.
// ---------------------------------------------------------------------------
__global__ __launch_bounds__(256) void fused_attn_kernel(const unsigned char* __restrict__ qf8,
                                                         const unsigned short* __restrict__ kbf,
                                                         const unsigned char* __restrict__ vf8,
                                                         const int* __restrict__ srcs,
                                                         const int* __restrict__ rowptr,
                                                         const float* __restrict__ triplet_h,
                                                         const float* __restrict__ g,
                                                         const float* __restrict__ b,
                                                         float* __restrict__ x,
                                                         unsigned short* __restrict__ xn)
{
    const int node = blockIdx.x * 4 + (threadIdx.x >> 6);
    const int lane = threadIdx.x & 63;
    int beg = rowptr[node];
    int end = rowptr[node + 1];
    beg = max(0, min(beg, N_EDGES));
    end = max(beg, min(end, N_EDGES));
    const int deg = end - beg;

    const ushort4 ku = *reinterpret_cast<const ushort4*>(
        kbf + (size_t)node * 256 + lane * 4);
    const float k0 = bf2f(ku.x) * ATT_SCALE, k1 = bf2f(ku.y) * ATT_SCALE;
    const float k2 = bf2f(ku.z) * ATT_SCALE, k3 = bf2f(ku.w) * ATT_SCALE;

    float dsum = 0.0f;
    float4 acc = {0.0f, 0.0f, 0.0f, 0.0f};

    for (int base = 0; base < deg; base += 64) {
        const int cnt = min(64, deg - base);
        const int idx = base + lane;
        const int sv = (idx < deg) ? srcs[beg + idx] : 0;   // coalesced prefetch
        int j = 0;
        for (; j + 4 <= cnt; j += 4) {
            const int s0 = __builtin_amdgcn_readlane(sv, j);
            const int s1 = __builtin_amdgcn_readlane(sv, j + 1);
            const int s2 = __builtin_amdgcn_readlane(sv, j + 2);
            const int s3 = __builtin_amdgcn_readlane(sv, j + 3);
            const unsigned int qa = *reinterpret_cast<const unsigned int*>(qf8 + (size_t)s0 * 256 + lane * 4);
            const unsigned int qb = *reinterpret_cast<const unsigned int*>(qf8 + (size_t)s1 * 256 + lane * 4);
            const unsigned int qc = *reinterpret_cast<const unsigned int*>(qf8 + (size_t)s2 * 256 + lane * 4);
            const unsigned int qd = *reinterpret_cast<const unsigned int*>(qf8 + (size_t)s3 * 256 + lane * 4);
            const unsigned int va = *reinterpret_cast<const unsigned int*>(vf8 + (size_t)s0 * 256 + lane * 4);
            const unsigned int vb = *reinterpret_cast<const unsigned int*>(vf8 + (size_t)s1 * 256 + lane * 4);
            const unsigned int vc = *reinterpret_cast<const unsigned int*>(vf8 + (size_t)s2 * 256 + lane * 4);
            const unsigned int vd = *reinterpret_cast<const unsigned int*>(vf8 + (size_t)s3 * 256 + lane * 4);
            float a0, a1, a2, a3;
            dec4_e4m3(qa, a0, a1, a2, a3);
            float p0 = a0 * k0 + a1 * k1 + a2 * k2 + a3 * k3;
            dec4_e4m3(qb, a0, a1, a2, a3);
            float p1 = a0 * k0 + a1 * k1 + a2 * k2 + a3 * k3;
            dec4_e4m3(qc, a0, a1, a2, a3);
            float p2 = a0 * k0 + a1 * k1 + a2 * k2 + a3 * k3;
            dec4_e4m3(qd, a0, a1, a2, a3);
            float p3 = a0 * k0 + a1 * k1 + a2 * k2 + a3 * k3;
            p0 += __shfl_xor(p0, 1, 64); p1 += __shfl_xor(p1, 1, 64);
            p2 += __shfl_xor(p2, 1, 64); p3 += __shfl_xor(p3, 1, 64);
            p0 += __shfl_xor(p0, 2, 64); p1 += __shfl_xor(p1, 2, 64);
            p2 += __shfl_xor(p2, 2, 64); p3 += __shfl_xor(p3, 2, 64);
            p0 += __shfl_xor(p0, 4, 64); p1 += __shfl_xor(p1, 4, 64);
            p2 += __shfl_xor(p2, 4, 64); p3 += __shfl_xor(p3, 4, 64);
            const float w0 = __expf(p0), w1 = __expf(p1), w2 = __expf(p2), w3 = __expf(p3);
            float v0, v1, v2, v3;
            dec4_e4m3(va, v0, v1, v2, v3);
            acc.x += w0 * v0; acc.y += w0 * v1; acc.z += w0 * v2; acc.w += w0 * v3;
            dec4_e4m3(vb, v0, v1, v2, v3);
            acc.x += w1 * v0; acc.y += w1 * v1; acc.z += w1 * v2; acc.w += w1 * v3;
            dec4_e4m3(vc, v0, v1, v2, v3);
            acc.x += w2 * v0; acc.y += w2 * v1; acc.z += w2 * v2; acc.w += w2 * v3;
            dec4_e4m3(vd, v0, v1, v2, v3);
            acc.x += w3 * v0; acc.y += w3 * v1; acc.z += w3 * v2; acc.w += w3 * v3;
            dsum += (w0 + w1) + (w2 + w3);
        }
        for (; j < cnt; ++j) {
            const int s0 = __builtin_amdgcn_readlane(sv, j);
            const unsigned int qa = *reinterpret_cast<const unsigned int*>(qf8 + (size_t)s0 * 256 + lane * 4);
            const unsigned int va = *reinterpret_cast<const unsigned int*>(vf8 + (size_t)s0 * 256 + lane * 4);
            float a0, a1, a2, a3;
            dec4_e4m3(qa, a0, a1, a2, a3);
            float p0 = a0 * k0 + a1 * k1 + a2 * k2 + a3 * k3;
            p0 += __shfl_xor(p0, 1, 64);
            p0 += __shfl_xor(p0, 2, 64);
            p0 += __shfl_xor(p0, 4, 64);
            const float w0 = __expf(p0);
            float v0, v1, v2, v3;
            dec4_e4m3(va, v0, v1, v2, v3);
            acc.x += w0 * v0; acc.y += w0 * v1; acc.z += w0 * v2; acc.w += w0 * v3;
            dsum += w0;
        }
    }
    const float inv = (deg > 0) ? 1.0f / dsum : 0.0f;

    const float4 th = *reinterpret_cast<const float4*>(
        triplet_h + (size_t)node * D + lane * 4);
    float4 xv;
    xv.x = th.x + acc.x * inv;
    xv.y = th.y + acc.y * inv;
    xv.z = th.z + acc.z * inv;
    xv.w = th.w + acc.w * inv;
    *reinterpret_cast<float4*>(x + (size_t)node * D + lane * 4) = xv;

    // LN2 across the wave
    float s  = xv.x + xv.y + xv.z + xv.w;
    float s2 = xv.x * xv.x + xv.y * xv.y + xv.z * xv.z + xv.w * xv.w;
#pragma unroll
    for (int o = 32; o > 0; o >>= 1) {
        s  += __shfl_xor(s,  o, 64);
        s2 += __shfl_xor(s2, o, 64);
    }
    const float mu  = s * (1.0f / D);
    const float var = s2 * (1.0f / D) - mu * mu;
    const float rs  = rsqrtf(var + LN_EPS);
    const float4 gg = *reinterpret_cast<const float4*>(g + lane * 4);
    const float4 bb = *reinterpret_cast<const float4*>(b + lane * 4);
    ushort4 o4;
    o4.x = f2bf((xv.x - mu) * rs * gg.x + bb.x);
    o4.y = f2bf((xv.y - mu) * rs * gg.y + bb.y);
    o4.z = f2bf((xv.z - mu) * rs * gg.z + bb.z);
    o4.w = f2bf((xv.w - mu) * rs * gg.w + bb.w);
    const size_t off = (((size_t)(node >> 4) * (D / 8) + (lane >> 1)) * 16 + (node & 15)) * 8
                       + (lane & 1) * 4;
    *reinterpret_cast<ushort4*>(xn + off) = o4;
}

// ---------------------------------------------------------------------------
extern "C" void kernel_launch(void* const* d_in, const int* in_sizes, int n_in,
                              void* d_out, int out_size, void* d_ws, size_t ws_size,
                              hipStream_t stream)
{
    const float* triplet_h = (const float*)d_in[0];
    const int*   src       = (const int*)d_in[1];
    const int*   dst       = (const int*)d_in[2];
    const float* Wqkv      = (const float*)d_in[3];
    const float* bqkv      = (const float*)d_in[4];
    const float* ln_attn_g = (const float*)d_in[5];
    const float* ln_attn_b = (const float*)d_in[6];
    const float* ln_res_g  = (const float*)d_in[7];
    const float* ln_res_b  = (const float*)d_in[8];
    const float* W_in      = (const float*)d_in[9];
    const float* b_in      = (const float*)d_in[10];
    const float* W_out     = (const float*)d_in[11];
    const float* b_out     = (const float*)d_in[12];
    float* out = (float*)d_out;

    // Workspace (~178 MB, under ceiling):
    char* w = (char*)d_ws;
    unsigned short* bufA = (unsigned short*)w;   // kbf (attn) then a1 (FFN)
    w += (size_t)M_PAD * DFF * sizeof(unsigned short);
    unsigned short* h_xn = (unsigned short*)w;  w += (size_t)M_PAD * D * sizeof(unsigned short);
    float*          x    = (float*)w;           w += (size_t)N_NODES * D * sizeof(float);
    unsigned char*  qf8  = (unsigned char*)w;   w += (size_t)N_NODES * 256;
    unsigned char*  vf8  = (unsigned char*)w;   w += (size_t)N_NODES * 256;
    unsigned short* Wqkv_pk = (unsigned short*)w; w += (size_t)D * D3 * sizeof(unsigned short);
    unsigned short* Win_pk  = (unsigned short*)w; w += (size_t)D * DFF * sizeof(unsigned short);
    unsigned short* Wout_pk = (unsigned short*)w; w += (size_t)DFF * D * sizeof(unsigned short);
    int* counts = (int*)w;  w += (size_t)N_NODES * sizeof(int);
    int* rowptr = (int*)w;  w += (size_t)(N_NODES + 1) * sizeof(int);
    int* rank   = (int*)w;  w += (size_t)N_EDGES * sizeof(int);
    int* srcs   = (int*)w;  w += (size_t)N_EDGES * sizeof(int);

    unsigned short* kbf = bufA;  // [40000][256] bf16 (k), dead after fused_attn
    unsigned short* a1  = bufA;  // [M_PAD/16][128][16][8] bf16 frag, live FFN only

    // ---- preprocessing (one launch: LN + weight packs + histogram+rank) ----
    (void)hipMemsetAsync(counts, 0, (size_t)N_NODES * sizeof(int), stream);
    prep_kernel<<<NB_LN + NB_PACK + NB_HIST, 256, 0, stream>>>(
        triplet_h, ln_attn_g, ln_attn_b, h_xn,
        Wqkv, W_in, W_out, Wqkv_pk, Win_pk, Wout_pk, dst, counts, rank);

    // ---- qkv GEMM + hidden CSR scan tail block ----
    mfma_gemm_kernel<0, D, D3><<<((M_PAD / 128 + 7) / 8) * 8 * (D3 / 128) + 1, 256, 0, stream>>>(
        h_xn, Wqkv_pk, bqkv, qf8, kbf, vf8, nullptr, counts, rowptr);

    // ---- atomic-free CSR fill ----
    fill_kernel<<<N_EDGES / 256, 256, 0, stream>>>(src, dst, rowptr, rank, srcs);

    // ---- attention + residual + LN2 ----
    fused_attn_kernel<<<N_NODES / 4, 256, 0, stream>>>(qf8, kbf, vf8, srcs, rowptr, triplet_h,
                                                       ln_res_g, ln_res_b, x, h_xn);

    // ---- FFN pair (kbf dead; a1 overwrites it; EPI1 stores pad rows too) ----
    mfma_gemm_kernel<1, D, DFF><<<((M_PAD / 128 + 7) / 8) * 8 * (DFF / 128), 256, 0, stream>>>(
        h_xn, Win_pk, b_in, a1, nullptr, nullptr, nullptr, nullptr, nullptr);
    mfma_gemm_kernel<2, DFF, D><<<((M_PAD / 128 + 7) / 8) * 8 * (D / 128), 256, 0, stream>>>(
        a1, Wout_pk, b_out, out, nullptr, nullptr, x, nullptr, nullptr);

    (void)in_sizes; (void)n_in; (void)out_size; (void)ws_size;
}